// Round 10
// baseline (139.417 us; speedup 1.0000x reference)
//
#include <hip/hip_runtime.h>
#include <hip/hip_bf16.h>

// Problem constants (Qwen3.5-VL vision attention)
constexpr int N_TOK  = 2048;
constexpr int DIM    = 1280;
constexpr int NHEAD  = 16;
constexpr int HD     = 80;
constexpr int QKV_N  = 3 * DIM;   // 3840

using bf16 = __hip_bfloat16;
typedef __attribute__((ext_vector_type(4))) float f32x4;
typedef __attribute__((ext_vector_type(8))) short short8;  // 8 bf16 = 4 VGPR

__device__ __forceinline__ float b2f(bf16 x) { return __bfloat162float(x); }
__device__ __forceinline__ bf16  f2b(float x) { return __float2bfloat16(x); }

// async global->LDS, 16B per lane; dest is wave-uniform base + lane*16
typedef const __attribute__((address_space(1))) unsigned int* gas_u32;
typedef __attribute__((address_space(3))) unsigned int* las_u32;
__device__ __forceinline__ void gload_lds16(const void* g, void* l) {
  __builtin_amdgcn_global_load_lds((gas_u32)g, (las_u32)l, 16, 0, 0);
}

// ---------------------------------------------------------------------------
// Fused prep: z=0 cast hs->bf16, z=1 transpose Wqkv, z=2 transpose Wproj.
// ---------------------------------------------------------------------------
__device__ __forceinline__ void transpose_body(const float* __restrict__ W,
                                               bf16* __restrict__ WT, int K, int N) {
  __shared__ float tile[32][33];
  const int n0 = blockIdx.x * 32, k0 = blockIdx.y * 32;
  const int tc = threadIdx.x & 31, tr = threadIdx.x >> 5;
#pragma unroll
  for (int r = tr; r < 32; r += 8)
    tile[r][tc] = W[(size_t)(k0 + r) * N + n0 + tc];
  __syncthreads();
#pragma unroll
  for (int r = tr; r < 32; r += 8)
    WT[(size_t)(n0 + r) * K + k0 + tc] = f2b(tile[tc][r]);
}

__global__ __launch_bounds__(256)
void prep_kernel(const float* __restrict__ hs, bf16* __restrict__ hsb,
                 const float* __restrict__ Wqkv, bf16* __restrict__ WqkvT,
                 const float* __restrict__ Wproj, bf16* __restrict__ WprojT) {
  if (blockIdx.z == 0) {
    const int bid = blockIdx.y * gridDim.x + blockIdx.x;
    if (bid >= (N_TOK * DIM) / 2048) return;
    const int i = bid * 2048 + threadIdx.x * 8;
    const float4 a = *reinterpret_cast<const float4*>(hs + i);
    const float4 b = *reinterpret_cast<const float4*>(hs + i + 4);
    __align__(16) bf16 w[8] = {f2b(a.x), f2b(a.y), f2b(a.z), f2b(a.w),
                               f2b(b.x), f2b(b.y), f2b(b.z), f2b(b.w)};
    *reinterpret_cast<short8*>(hsb + i) = *reinterpret_cast<const short8*>(w);
  } else if (blockIdx.z == 1) {
    transpose_body(Wqkv, WqkvT, DIM, QKV_N);           // grid (120,40)
  } else {
    if (blockIdx.x >= DIM / 32) return;
    transpose_body(Wproj, WprojT, DIM, DIM);           // (40,40)
  }
}

// ---------------------------------------------------------------------------
// m97-style MFMA GEMM (R7-verified): C = A(bf16) @ BT(bf16) + bias(fp32)
// BM=BN=128, BK=64, 4 waves, global_load_lds w16 + pre-swizzled source.
// ---------------------------------------------------------------------------
template <int OBF>  // 1: C bf16, 0: C fp32
__global__ __launch_bounds__(256)
void mfma_gemm(const bf16* __restrict__ A, const bf16* __restrict__ BT,
               const float* __restrict__ bias, void* __restrict__ C,
               int M, int N, int K) {
  __shared__ bf16 As[128 * 64];
  __shared__ bf16 Bs[128 * 64];
  const int tid = threadIdx.x;
  const int wid = tid >> 6, lane = tid & 63;
  const int lm = lane & 15, kg = lane >> 4;
  const int wm = (wid >> 1) * 64, wn = (wid & 1) * 64;
  const int m0 = blockIdx.y * 128, n0 = blockIdx.x * 128;

  const int srow = lane >> 3;
  const int sblk = (lane & 7) ^ srow;

  f32x4 acc[4][4];
#pragma unroll
  for (int i = 0; i < 4; ++i)
#pragma unroll
    for (int j = 0; j < 4; ++j) acc[i][j] = (f32x4){0.f, 0.f, 0.f, 0.f};

  for (int k0 = 0; k0 < K; k0 += 64) {
#pragma unroll
    for (int i = 0; i < 4; ++i) {
      const int slot = i * 4 + wid;
      const int row = slot * 8 + srow;
      gload_lds16(A + (size_t)(m0 + row) * K + k0 + sblk * 8, &As[slot * 512]);
      gload_lds16(BT + (size_t)(n0 + row) * K + k0 + sblk * 8, &Bs[slot * 512]);
    }
    __syncthreads();

#pragma unroll
    for (int kh = 0; kh < 2; ++kh) {
      short8 af[4], bfr[4];
#pragma unroll
      for (int t = 0; t < 4; ++t) {
        const int ar = wm + t * 16 + lm;
        af[t] = *reinterpret_cast<const short8*>(
            &As[ar * 64 + ((kh * 4 + kg) ^ (ar & 7)) * 8]);
        const int br = wn + t * 16 + lm;
        bfr[t] = *reinterpret_cast<const short8*>(
            &Bs[br * 64 + ((kh * 4 + kg) ^ (br & 7)) * 8]);
      }
#pragma unroll
      for (int mi = 0; mi < 4; ++mi)
#pragma unroll
        for (int ni = 0; ni < 4; ++ni)
          acc[mi][ni] = __builtin_amdgcn_mfma_f32_16x16x32_bf16(
              af[mi], bfr[ni], acc[mi][ni], 0, 0, 0);
    }
    __syncthreads();
  }

#pragma unroll
  for (int mi = 0; mi < 4; ++mi) {
#pragma unroll
    for (int ni = 0; ni < 4; ++ni) {
      const int col = n0 + wn + ni * 16 + lm;
      const float bv = bias[col];
#pragma unroll
      for (int r = 0; r < 4; ++r) {
        const int row = m0 + wm + mi * 16 + kg * 4 + r;
        const float v = acc[mi][ni][r] + bv;
        if constexpr (OBF)
          ((bf16*)C)[(size_t)row * N + col] = f2b(v);
        else
          ((float*)C)[(size_t)row * N + col] = v;
      }
    }
  }
}

// ---------------------------------------------------------------------------
// RoPE on q and k (in-place on bf16 qkv workspace). cos/sin fp32.
// ---------------------------------------------------------------------------
__global__ void rope_kernel(bf16* __restrict__ qkv, const float* __restrict__ cosb,
                            const float* __restrict__ sinb) {
  constexpr int HALF = HD / 2;  // 40
  int idx = blockIdx.x * blockDim.x + threadIdx.x;
  int n     = idx / (2 * NHEAD * HALF);
  int rem   = idx % (2 * NHEAD * HALF);
  int which = rem / (NHEAD * HALF);
  int rem2  = rem % (NHEAD * HALF);
  int h     = rem2 / HALF;
  int d     = rem2 % HALF;
  size_t base = (size_t)n * QKV_N + which * DIM + h * HD;
  float x1 = b2f(qkv[base + d]), x2 = b2f(qkv[base + d + HALF]);
  float c1 = cosb[n * HD + d], c2 = cosb[n * HD + d + HALF];
  float s1 = sinb[n * HD + d], s2 = sinb[n * HD + d + HALF];
  qkv[base + d]        = f2b(x1 * c1 - x2 * s1);
  qkv[base + d + HALF] = f2b(x2 * c2 + x1 * s2);
}

// ---------------------------------------------------------------------------
// MFMA flash attention, R10: R9 structure + 2-way KEY SPLIT (flash-decode).
// blockIdx.y = seg*2 + khalf; each block handles half the seg's chunks and
// writes a normalized partial: pO[q][h][kh][80] (bf16, = o/l) and
// pML[q][h][kh] = (m, l) fp32. 512 active blocks -> 2 blocks/CU (TLP hides
// barriers). combine_kernel merges the two halves exactly.
// ---------------------------------------------------------------------------
constexpr int KC   = 64;   // keys per chunk
constexpr int KSTR = 104;  // >=96 (in-row d-chunks), 208B rows: 2-way banks
constexpr int VSTR = 88;   // 176B rows: 16B-aligned reads, ~4-way writes
constexpr int PSTR = 72;   // 144B rows

__global__ __launch_bounds__(512)
void attn_mfma_kernel(const bf16* __restrict__ qkv, const int* __restrict__ cu,
                      bf16* __restrict__ pO, float2* __restrict__ pML) {
  __shared__ bf16 Ks[2][KC * KSTR];      // 26624 B, cols 80..103 zeroed
  __shared__ bf16 Vt[HD * VSTR];         // 14080 B [d][key^swz]
  __shared__ bf16 Pl[8 * 16 * PSTR];     // 18432 B per-wave [q][key]

  const int h = blockIdx.z;
  const int seg = blockIdx.y >> 1, khalf = blockIdx.y & 1;
  const int s0 = cu[seg], s1 = cu[seg + 1];
  if (s0 + (int)blockIdx.x * 128 >= s1) return;  // uniform early-exit

  const int tid  = threadIdx.x;
  const int wid  = tid >> 6, lane = tid & 63;
  const int lm = lane & 15, kg = lane >> 4;
  const int qrow = s0 + blockIdx.x * 128 + wid * 16 + lm;
  const float scale = 0.11180339887498949f;  // 80^-0.5

  // this half's chunk range
  const int nch = (s1 - s0 + KC - 1) / KC;
  const int c0 = khalf ? (nch + 1) / 2 : 0;
  const int c1 = khalf ? nch : (nch + 1) / 2;

  // partial output pointers for this lane's query
  const size_t pbaseO = ((size_t)(qrow * NHEAD + h) * 2 + khalf) * HD;
  const int    pbaseM = (qrow * NHEAD + h) * 2 + khalf;

  if (c0 >= c1) {  // empty half (tiny segment): write zero partial
    if (qrow < s1) {
#pragma unroll
      for (int dt = 0; dt < 5; ++dt) {
        __align__(8) bf16 w[4] = {f2b(0.f), f2b(0.f), f2b(0.f), f2b(0.f)};
        *reinterpret_cast<uint2*>(pO + pbaseO + dt * 16 + kg * 4) =
            *reinterpret_cast<const uint2*>(w);
      }
      if (kg == 0) pML[pbaseM] = make_float2(-1e30f, 0.f);
    }
    return;
  }

  // zero-fill Ks pad columns 80..103 in BOTH buffers
  if (tid < 384) {
    int b = tid / 192, rem = tid % 192, r = rem / 3, sl = rem % 3;
    *reinterpret_cast<short8*>(&Ks[b][r * KSTR + 80 + sl * 8]) =
        (short8){0, 0, 0, 0, 0, 0, 0, 0};
  }

  // Q B-fragments: lane holds Q[q=lm][d = ck*32 + kg*8 .. +7], zero-padded
  short8 qa[3];
#pragma unroll
  for (int ck = 0; ck < 3; ++ck) {
    const int dbase = ck * 32 + kg * 8;
    if (qrow < s1 && dbase < HD)
      qa[ck] = *reinterpret_cast<const short8*>(
          qkv + (size_t)qrow * QKV_N + h * HD + dbase);
    else
      qa[ck] = (short8){0, 0, 0, 0, 0, 0, 0, 0};
  }

  // prefetch regs: K 640 slots over 512 thr (2 rounds), V 160 thr x 4 keys
  short8 kreg[2], vreg[4];
  const int vgrp = tid / 10, vsl = tid % 10;  // valid for tid<160
  auto issueK = [&](int c) {
    const int k0 = s0 + c * KC;
    {
      const int r = min(k0 + tid / 10, s1 - 1);
      kreg[0] = *reinterpret_cast<const short8*>(
          qkv + (size_t)r * QKV_N + DIM + h * HD + (tid % 10) * 8);
    }
    if (tid < 128) {
      const int s = tid + 512;
      const int r = min(k0 + s / 10, s1 - 1);
      kreg[1] = *reinterpret_cast<const short8*>(
          qkv + (size_t)r * QKV_N + DIM + h * HD + (s % 10) * 8);
    }
  };
  auto commitK = [&](int buf) {
    *reinterpret_cast<short8*>(&Ks[buf][(tid / 10) * KSTR + (tid % 10) * 8]) =
        kreg[0];
    if (tid < 128) {
      const int s = tid + 512;
      *reinterpret_cast<short8*>(&Ks[buf][(s / 10) * KSTR + (s % 10) * 8]) =
          kreg[1];
    }
  };
  auto issueV = [&](int c) {
    if (tid < 160) {
      const int k0 = s0 + c * KC;
#pragma unroll
      for (int e = 0; e < 4; ++e) {
        const int r = min(k0 + vgrp * 4 + e, s1 - 1);
        vreg[e] = *reinterpret_cast<const short8*>(
            qkv + (size_t)r * QKV_N + 2 * DIM + h * HD + vsl * 8);
      }
    }
  };
  auto commitV = [&]() {
    if (tid < 160) {
      const int r0 = vgrp * 4;
      const int swz = (vsl & 7) << 3;
#pragma unroll
      for (int de = 0; de < 8; ++de) {
        __align__(8) bf16 w[4] = {reinterpret_cast<const bf16*>(&vreg[0])[de],
                                  reinterpret_cast<const bf16*>(&vreg[1])[de],
                                  reinterpret_cast<const bf16*>(&vreg[2])[de],
                                  reinterpret_cast<const bf16*>(&vreg[3])[de]};
        *reinterpret_cast<uint2*>(&Vt[(vsl * 8 + de) * VSTR + (r0 ^ swz)]) =
            *reinterpret_cast<const uint2*>(w);
      }
    }
  };

  f32x4 oacc[5];
#pragma unroll
  for (int dt = 0; dt < 5; ++dt) oacc[dt] = (f32x4){0.f, 0.f, 0.f, 0.f};
  float m = -1e30f, l = 0.f;
  const int plbase = (wid * 16 + lm) * PSTR;

  issueK(c0);
  issueV(c0);
  commitK(0);
  if (c0 + 1 < c1) issueK(c0 + 1);
  __syncthreads();

  for (int c = c0; c < c1; ++c) {
    const int cur = (c - c0) & 1;
    const int nk = min(KC, s1 - (s0 + c * KC));

    // 1. commit V(c) into the single Vt buffer (readers drained at endbar)
    commitV();

    // 2. S^T = K . Q^T : 4 key-tiles x 3 d-chunks
    f32x4 sc[4];
    __builtin_amdgcn_s_setprio(1);
#pragma unroll
    for (int mi = 0; mi < 4; ++mi) {
      sc[mi] = (f32x4){0.f, 0.f, 0.f, 0.f};
#pragma unroll
      for (int ck = 0; ck < 3; ++ck) {
        short8 ka = *reinterpret_cast<const short8*>(
            &Ks[cur][(mi * 16 + lm) * KSTR + ck * 32 + kg * 8]);
        sc[mi] = __builtin_amdgcn_mfma_f32_16x16x32_bf16(ka, qa[ck], sc[mi], 0, 0, 0);
      }
    }
    __builtin_amdgcn_s_setprio(0);

    // 3+4. pipeline: commit K(c+1), issue V(c+1), issue K(c+2)
    if (c + 1 < c1) {
      commitK(cur ^ 1);
      issueV(c + 1);
    }
    if (c + 2 < c1) issueK(c + 2);

    // 5. scale, tail-mask, online softmax (defer-max), pack P
#pragma unroll
    for (int mi = 0; mi < 4; ++mi) sc[mi] *= scale;
    if (nk < KC) {
#pragma unroll
      for (int mi = 0; mi < 4; ++mi)
#pragma unroll
        for (int r = 0; r < 4; ++r)
          if (mi * 16 + kg * 4 + r >= nk) sc[mi][r] = -1e30f;
    }
    f32x4 m4 = sc[0];
#pragma unroll
    for (int mi = 1; mi < 4; ++mi) {
      m4[0] = fmaxf(m4[0], sc[mi][0]); m4[1] = fmaxf(m4[1], sc[mi][1]);
      m4[2] = fmaxf(m4[2], sc[mi][2]); m4[3] = fmaxf(m4[3], sc[mi][3]);
    }
    float rm = fmaxf(fmaxf(m4[0], m4[1]), fmaxf(m4[2], m4[3]));
    rm = fmaxf(rm, __shfl_xor(rm, 16));
    rm = fmaxf(rm, __shfl_xor(rm, 32));
    const float mnew = fmaxf(m, rm);
    if (!__all(mnew - m <= 8.0f)) {  // rescale only on real max growth
      const float fs = __expf(m - mnew);
      m = mnew;
      l *= fs;
#pragma unroll
      for (int dt = 0; dt < 5; ++dt) oacc[dt] *= fs;
    }
    float rs = 0.f;
    f32x4 pp[4];
#pragma unroll
    for (int mi = 0; mi < 4; ++mi) {
#pragma unroll
      for (int r = 0; r < 4; ++r) {
        pp[mi][r] = __expf(sc[mi][r] - m);  // bounded by e^8
        rs += pp[mi][r];
      }
    }
    rs += __shfl_xor(rs, 16);
    rs += __shfl_xor(rs, 32);
    l += rs;
#pragma unroll
    for (int mi = 0; mi < 4; ++mi) {
      __align__(8) bf16 w[4] = {f2b(pp[mi][0]), f2b(pp[mi][1]),
                                f2b(pp[mi][2]), f2b(pp[mi][3])};
      *reinterpret_cast<uint2*>(&Pl[plbase + mi * 16 + kg * 4]) =
          *reinterpret_cast<const uint2*>(w);
    }

    __syncthreads();  // MIDBAR: Vt(c) visible to all waves before PV

    // 7. O^T += V^T . P^T : 2 key-chunks x 5 d-tiles
    __builtin_amdgcn_s_setprio(1);
#pragma unroll
    for (int kc = 0; kc < 2; ++kc) {
      short8 pb = *reinterpret_cast<const short8*>(&Pl[plbase + kc * 32 + kg * 8]);
#pragma unroll
      for (int dt = 0; dt < 5; ++dt) {
        const int d = dt * 16 + lm;
        short8 va = *reinterpret_cast<const short8*>(
            &Vt[d * VSTR + ((kc * 32 + kg * 8) ^ (((d >> 3) & 7) << 3))]);
        oacc[dt] = __builtin_amdgcn_mfma_f32_16x16x32_bf16(va, pb, oacc[dt], 0, 0, 0);
      }
    }
    __builtin_amdgcn_s_setprio(0);

    __syncthreads();  // ENDBAR: PV(c) reads drained -> next commitV safe
  }

  // ---- epilogue: normalized partial o/l (bf16) + (m,l) fp32 ----
  if (qrow < s1) {
    const float inv = 1.f / l;
#pragma unroll
    for (int dt = 0; dt < 5; ++dt) {
      __align__(8) bf16 w[4] = {f2b(oacc[dt][0] * inv), f2b(oacc[dt][1] * inv),
                                f2b(oacc[dt][2] * inv), f2b(oacc[dt][3] * inv)};
      *reinterpret_cast<uint2*>(pO + pbaseO + dt * 16 + kg * 4) =
          *reinterpret_cast<const uint2*>(w);
    }
    if (kg == 0) pML[pbaseM] = make_float2(m, l);
  }
}

// ---------------------------------------------------------------------------
// Combine the two key-half partials: out = (w0*o0 + w1*o1)/(w0+w1),
// w_i = l_i * exp(m_i - max(m)).  One thread per (q, h).
// ---------------------------------------------------------------------------
__global__ __launch_bounds__(256)
void combine_kernel(const bf16* __restrict__ pO, const float2* __restrict__ pML,
                    bf16* __restrict__ attn_out) {
  const int idx = blockIdx.x * 256 + threadIdx.x;  // q*16 + h
  const float2 ml0 = pML[idx * 2], ml1 = pML[idx * 2 + 1];
  const float M = fmaxf(ml0.x, ml1.x);
  float w0 = ml0.y * __expf(ml0.x - M);
  float w1 = ml1.y * __expf(ml1.x - M);
  const float inv = 1.f / (w0 + w1);
  w0 *= inv; w1 *= inv;
  const bf16* a = pO + (size_t)idx * (2 * HD);
  const bf16* b = a + HD;
  const int q = idx >> 4, h = idx & 15;
  bf16* o = attn_out + (size_t)q * DIM + h * HD;
#pragma unroll
  for (int s = 0; s < 10; ++s) {
    short8 av = *reinterpret_cast<const short8*>(a + s * 8);
    short8 bv = *reinterpret_cast<const short8*>(b + s * 8);
    __align__(16) bf16 w[8];
#pragma unroll
    for (int e = 0; e < 8; ++e)
      w[e] = f2b(w0 * b2f(reinterpret_cast<const bf16*>(&av)[e]) +
                 w1 * b2f(reinterpret_cast<const bf16*>(&bv)[e]));
    *reinterpret_cast<short8*>(o + s * 8) = *reinterpret_cast<const short8*>(w);
  }
}

// ---------------------------------------------------------------------------
extern "C" void kernel_launch(void* const* d_in, const int* in_sizes, int n_in,
                              void* d_out, int out_size, void* d_ws, size_t ws_size,
                              hipStream_t stream) {
  const float* hs    = (const float*)d_in[0];
  const int*   cu    = (const int*)d_in[1];
  const float* cosb  = (const float*)d_in[2];
  const float* sinb  = (const float*)d_in[3];
  const float* Wqkv  = (const float*)d_in[4];
  const float* bqkv  = (const float*)d_in[5];
  const float* Wproj = (const float*)d_in[6];
  const float* bproj = (const float*)d_in[7];

  // ws layout (39.3 MB): qkv 15.73 | attn_out 5.24 | WprojT 3.28 |
  //   WqkvT 9.83 | hsb 5.24.  WqkvT+hsb (contiguous, 15.07 MB) are DEAD after
  //   gemm1 and overlaid by attn partials: pO 10.49 MB + pML 0.52 MB.
  bf16* qkv      = (bf16*)d_ws;
  bf16* attn_out = qkv + (size_t)N_TOK * QKV_N;
  bf16* WprojT   = attn_out + (size_t)N_TOK * DIM;
  bf16* WqkvT    = WprojT + (size_t)DIM * DIM;
  bf16* hsb      = WqkvT + (size_t)QKV_N * DIM;
  bf16*   pO  = WqkvT;                                   // 2048*16*2*80 bf16
  float2* pML = (float2*)(pO + (size_t)N_TOK * NHEAD * 2 * HD);

  // 0) fused prep: cast hs + transpose both weights
  prep_kernel<<<dim3(QKV_N / 32, DIM / 32, 3), 256, 0, stream>>>(
      hs, hsb, Wqkv, WqkvT, Wproj, WprojT);

  // 1) qkv = bf16(hsb @ Wqkv + bqkv)
  mfma_gemm<1><<<dim3(QKV_N / 128, N_TOK / 128), 256, 0, stream>>>(
      hsb, WqkvT, bqkv, qkv, N_TOK, QKV_N, DIM);

  // 2) RoPE on q,k
  rope_kernel<<<(N_TOK * 2 * NHEAD * (HD / 2)) / 256, 256, 0, stream>>>(
      qkv, cosb, sinb);

  // 3) MFMA flash attention, 2-way key split -> partials (overlays WqkvT/hsb)
  int nseg = in_sizes[1] - 1;
  attn_mfma_kernel<<<dim3(N_TOK / 128, nseg * 2, NHEAD), 512, 0, stream>>>(
      qkv, cu, pO, pML);

  // 3b) combine partials -> attn_out (bf16)
  combine_kernel<<<(N_TOK * NHEAD) / 256, 256, 0, stream>>>(pO, pML, attn_out);

  // 4) out = attn_out @ Wproj + bproj (fp32 out)
  mfma_gemm<0><<<dim3(DIM / 128, N_TOK / 128), 256, 0, stream>>>(
      attn_out, WprojT, bproj, d_out, N_TOK, DIM, DIM);
}

// Round 11
// 124.160 us; speedup vs baseline: 1.1229x; 1.1229x over previous
//
#include <hip/hip_runtime.h>
#include <hip/hip_bf16.h>

// Problem constants (Qwen3.5-VL vision attention)
constexpr int N_TOK  = 2048;
constexpr int DIM    = 1280;
constexpr int NHEAD  = 16;
constexpr int HD     = 80;
constexpr int QKV_N  = 3 * DIM;   // 3840

using bf16 = __hip_bfloat16;
typedef __attribute__((ext_vector_type(4))) float f32x4;
typedef __attribute__((ext_vector_type(8))) short short8;  // 8 bf16 = 4 VGPR

__device__ __forceinline__ float b2f(bf16 x) { return __bfloat162float(x); }
__device__ __forceinline__ bf16  f2b(float x) { return __float2bfloat16(x); }

// async global->LDS, 16B per lane; dest is wave-uniform base + lane*16
typedef const __attribute__((address_space(1))) unsigned int* gas_u32;
typedef __attribute__((address_space(3))) unsigned int* las_u32;
__device__ __forceinline__ void gload_lds16(const void* g, void* l) {
  __builtin_amdgcn_global_load_lds((gas_u32)g, (las_u32)l, 16, 0, 0);
}

// ---------------------------------------------------------------------------
// Fused prep: z=0 cast hs->bf16, z=1 transpose Wqkv, z=2 transpose Wproj.
// ---------------------------------------------------------------------------
__device__ __forceinline__ void transpose_body(const float* __restrict__ W,
                                               bf16* __restrict__ WT, int K, int N) {
  __shared__ float tile[32][33];
  const int n0 = blockIdx.x * 32, k0 = blockIdx.y * 32;
  const int tc = threadIdx.x & 31, tr = threadIdx.x >> 5;
#pragma unroll
  for (int r = tr; r < 32; r += 8)
    tile[r][tc] = W[(size_t)(k0 + r) * N + n0 + tc];
  __syncthreads();
#pragma unroll
  for (int r = tr; r < 32; r += 8)
    WT[(size_t)(n0 + r) * K + k0 + tc] = f2b(tile[tc][r]);
}

__global__ __launch_bounds__(256)
void prep_kernel(const float* __restrict__ hs, bf16* __restrict__ hsb,
                 const float* __restrict__ Wqkv, bf16* __restrict__ WqkvT,
                 const float* __restrict__ Wproj, bf16* __restrict__ WprojT) {
  if (blockIdx.z == 0) {
    const int bid = blockIdx.y * gridDim.x + blockIdx.x;
    if (bid >= (N_TOK * DIM) / 2048) return;
    const int i = bid * 2048 + threadIdx.x * 8;
    const float4 a = *reinterpret_cast<const float4*>(hs + i);
    const float4 b = *reinterpret_cast<const float4*>(hs + i + 4);
    __align__(16) bf16 w[8] = {f2b(a.x), f2b(a.y), f2b(a.z), f2b(a.w),
                               f2b(b.x), f2b(b.y), f2b(b.z), f2b(b.w)};
    *reinterpret_cast<short8*>(hsb + i) = *reinterpret_cast<const short8*>(w);
  } else if (blockIdx.z == 1) {
    transpose_body(Wqkv, WqkvT, DIM, QKV_N);           // grid (120,40)
  } else {
    if (blockIdx.x >= DIM / 32) return;
    transpose_body(Wproj, WprojT, DIM, DIM);           // (40,40)
  }
}

// ---------------------------------------------------------------------------
// m97-style MFMA GEMM (R7-verified): C = A(bf16) @ BT(bf16) + bias(fp32)
// BM=BN=128, BK=64, 4 waves, global_load_lds w16 + pre-swizzled source.
// ---------------------------------------------------------------------------
template <int OBF>  // 1: C bf16, 0: C fp32
__global__ __launch_bounds__(256)
void mfma_gemm(const bf16* __restrict__ A, const bf16* __restrict__ BT,
               const float* __restrict__ bias, void* __restrict__ C,
               int M, int N, int K) {
  __shared__ bf16 As[128 * 64];
  __shared__ bf16 Bs[128 * 64];
  const int tid = threadIdx.x;
  const int wid = tid >> 6, lane = tid & 63;
  const int lm = lane & 15, kg = lane >> 4;
  const int wm = (wid >> 1) * 64, wn = (wid & 1) * 64;
  const int m0 = blockIdx.y * 128, n0 = blockIdx.x * 128;

  const int srow = lane >> 3;
  const int sblk = (lane & 7) ^ srow;

  f32x4 acc[4][4];
#pragma unroll
  for (int i = 0; i < 4; ++i)
#pragma unroll
    for (int j = 0; j < 4; ++j) acc[i][j] = (f32x4){0.f, 0.f, 0.f, 0.f};

  for (int k0 = 0; k0 < K; k0 += 64) {
#pragma unroll
    for (int i = 0; i < 4; ++i) {
      const int slot = i * 4 + wid;
      const int row = slot * 8 + srow;
      gload_lds16(A + (size_t)(m0 + row) * K + k0 + sblk * 8, &As[slot * 512]);
      gload_lds16(BT + (size_t)(n0 + row) * K + k0 + sblk * 8, &Bs[slot * 512]);
    }
    __syncthreads();

#pragma unroll
    for (int kh = 0; kh < 2; ++kh) {
      short8 af[4], bfr[4];
#pragma unroll
      for (int t = 0; t < 4; ++t) {
        const int ar = wm + t * 16 + lm;
        af[t] = *reinterpret_cast<const short8*>(
            &As[ar * 64 + ((kh * 4 + kg) ^ (ar & 7)) * 8]);
        const int br = wn + t * 16 + lm;
        bfr[t] = *reinterpret_cast<const short8*>(
            &Bs[br * 64 + ((kh * 4 + kg) ^ (br & 7)) * 8]);
      }
#pragma unroll
      for (int mi = 0; mi < 4; ++mi)
#pragma unroll
        for (int ni = 0; ni < 4; ++ni)
          acc[mi][ni] = __builtin_amdgcn_mfma_f32_16x16x32_bf16(
              af[mi], bfr[ni], acc[mi][ni], 0, 0, 0);
    }
    __syncthreads();
  }

#pragma unroll
  for (int mi = 0; mi < 4; ++mi) {
#pragma unroll
    for (int ni = 0; ni < 4; ++ni) {
      const int col = n0 + wn + ni * 16 + lm;
      const float bv = bias[col];
#pragma unroll
      for (int r = 0; r < 4; ++r) {
        const int row = m0 + wm + mi * 16 + kg * 4 + r;
        const float v = acc[mi][ni][r] + bv;
        if constexpr (OBF)
          ((bf16*)C)[(size_t)row * N + col] = f2b(v);
        else
          ((float*)C)[(size_t)row * N + col] = v;
      }
    }
  }
}

// ---------------------------------------------------------------------------
// RoPE on q and k (in-place on bf16 qkv workspace). cos/sin fp32.
// ---------------------------------------------------------------------------
__global__ void rope_kernel(bf16* __restrict__ qkv, const float* __restrict__ cosb,
                            const float* __restrict__ sinb) {
  constexpr int HALF = HD / 2;  // 40
  int idx = blockIdx.x * blockDim.x + threadIdx.x;
  int n     = idx / (2 * NHEAD * HALF);
  int rem   = idx % (2 * NHEAD * HALF);
  int which = rem / (NHEAD * HALF);
  int rem2  = rem % (NHEAD * HALF);
  int h     = rem2 / HALF;
  int d     = rem2 % HALF;
  size_t base = (size_t)n * QKV_N + which * DIM + h * HD;
  float x1 = b2f(qkv[base + d]), x2 = b2f(qkv[base + d + HALF]);
  float c1 = cosb[n * HD + d], c2 = cosb[n * HD + d + HALF];
  float s1 = sinb[n * HD + d], s2 = sinb[n * HD + d + HALF];
  qkv[base + d]        = f2b(x1 * c1 - x2 * s1);
  qkv[base + d + HALF] = f2b(x2 * c2 + x1 * s2);
}

// ---------------------------------------------------------------------------
// MFMA flash attention, R11 = R9 structure (key-split reverted) +
//  - LAZY softmax: common path has NO cross-lane ops (per-lane max guard via
//    wave-uniform __all; per-lane partial l reduced once in epilogue). First
//    chunk always takes the full-reduce path (m = -1e30).
//  - XCD-aware block remap: 1D grid, l = (p&7)*(nblk/8) + p/8 so each XCD
//    keeps ~2 heads' K/V slices L2-resident (FETCH was 2.8x over-read).
// ---------------------------------------------------------------------------
constexpr int KC   = 64;   // keys per chunk
constexpr int KSTR = 104;  // >=96 (in-row d-chunks), 208B rows: 2-way banks
constexpr int VSTR = 88;   // 176B rows: 16B-aligned reads, ~2-way
constexpr int PSTR = 72;   // 144B rows

__global__ __launch_bounds__(512)
void attn_mfma_kernel(const bf16* __restrict__ qkv, const int* __restrict__ cu,
                      bf16* __restrict__ out, int nseg) {
  __shared__ bf16 Ks[2][KC * KSTR];      // 26624 B, cols 80..103 zeroed
  __shared__ bf16 Vt[HD * VSTR];         // 14080 B [d][key^swz]
  __shared__ bf16 Pl[8 * 16 * PSTR];     // 18432 B per-wave [q][key]

  // XCD-aware remap (bijective: gridDim.x % 8 == 0)
  const int p = blockIdx.x;
  const int lidx = (p & 7) * (gridDim.x >> 3) + (p >> 3);
  const int xt  = lidx & 15;             // q-tile (N_TOK/128 = 16)
  const int seg = (lidx >> 4) % nseg;
  const int h   = (lidx >> 4) / nseg;

  const int s0 = cu[seg], s1 = cu[seg + 1];
  if (s0 + xt * 128 >= s1) return;  // uniform early-exit

  const int tid  = threadIdx.x;
  const int wid  = tid >> 6, lane = tid & 63;
  const int lm = lane & 15, kg = lane >> 4;
  const int qrow = s0 + xt * 128 + wid * 16 + lm;
  const float scale = 0.11180339887498949f;  // 80^-0.5

  // zero-fill Ks pad columns 80..103 in BOTH buffers
  if (tid < 384) {
    int b = tid / 192, rem = tid % 192, r = rem / 3, sl = rem % 3;
    *reinterpret_cast<short8*>(&Ks[b][r * KSTR + 80 + sl * 8]) =
        (short8){0, 0, 0, 0, 0, 0, 0, 0};
  }

  // Q B-fragments: lane holds Q[q=lm][d = ck*32 + kg*8 .. +7], zero-padded
  short8 qa[3];
#pragma unroll
  for (int ck = 0; ck < 3; ++ck) {
    const int dbase = ck * 32 + kg * 8;
    if (qrow < s1 && dbase < HD)
      qa[ck] = *reinterpret_cast<const short8*>(
          qkv + (size_t)qrow * QKV_N + h * HD + dbase);
    else
      qa[ck] = (short8){0, 0, 0, 0, 0, 0, 0, 0};
  }

  // prefetch regs: K 640 slots over 512 thr (2 rounds), V 160 thr x 4 keys
  short8 kreg[2], vreg[4];
  const int vgrp = tid / 10, vsl = tid % 10;  // valid for tid<160
  auto issueK = [&](int c) {
    const int k0 = s0 + c * KC;
    {
      const int r = min(k0 + tid / 10, s1 - 1);
      kreg[0] = *reinterpret_cast<const short8*>(
          qkv + (size_t)r * QKV_N + DIM + h * HD + (tid % 10) * 8);
    }
    if (tid < 128) {
      const int s = tid + 512;
      const int r = min(k0 + s / 10, s1 - 1);
      kreg[1] = *reinterpret_cast<const short8*>(
          qkv + (size_t)r * QKV_N + DIM + h * HD + (s % 10) * 8);
    }
  };
  auto commitK = [&](int buf) {
    *reinterpret_cast<short8*>(&Ks[buf][(tid / 10) * KSTR + (tid % 10) * 8]) =
        kreg[0];
    if (tid < 128) {
      const int s = tid + 512;
      *reinterpret_cast<short8*>(&Ks[buf][(s / 10) * KSTR + (s % 10) * 8]) =
          kreg[1];
    }
  };
  auto issueV = [&](int c) {
    if (tid < 160) {
      const int k0 = s0 + c * KC;
#pragma unroll
      for (int e = 0; e < 4; ++e) {
        const int r = min(k0 + vgrp * 4 + e, s1 - 1);
        vreg[e] = *reinterpret_cast<const short8*>(
            qkv + (size_t)r * QKV_N + 2 * DIM + h * HD + vsl * 8);
      }
    }
  };
  auto commitV = [&]() {
    if (tid < 160) {
      const int r0 = vgrp * 4;
      const int swz = (vsl & 7) << 3;
#pragma unroll
      for (int de = 0; de < 8; ++de) {
        __align__(8) bf16 w[4] = {reinterpret_cast<const bf16*>(&vreg[0])[de],
                                  reinterpret_cast<const bf16*>(&vreg[1])[de],
                                  reinterpret_cast<const bf16*>(&vreg[2])[de],
                                  reinterpret_cast<const bf16*>(&vreg[3])[de]};
        *reinterpret_cast<uint2*>(&Vt[(vsl * 8 + de) * VSTR + (r0 ^ swz)]) =
            *reinterpret_cast<const uint2*>(w);
      }
    }
  };

  f32x4 oacc[5];
#pragma unroll
  for (int dt = 0; dt < 5; ++dt) oacc[dt] = (f32x4){0.f, 0.f, 0.f, 0.f};
  float m = -1e30f, l = 0.f;   // l is a PER-LANE partial (reduced in epilogue)
  const int plbase = (wid * 16 + lm) * PSTR;
  const int nch = (s1 - s0 + KC - 1) / KC;

  issueK(0);
  issueV(0);
  commitK(0);
  if (nch > 1) issueK(1);
  __syncthreads();

  for (int c = 0; c < nch; ++c) {
    const int cur = c & 1;
    const int nk = min(KC, s1 - (s0 + c * KC));

    // 1. commit V(c) into the single Vt buffer (readers drained at endbar)
    commitV();

    // 2. S^T = K . Q^T : 4 key-tiles x 3 d-chunks
    f32x4 sc[4];
    __builtin_amdgcn_s_setprio(1);
#pragma unroll
    for (int mi = 0; mi < 4; ++mi) {
      sc[mi] = (f32x4){0.f, 0.f, 0.f, 0.f};
#pragma unroll
      for (int ck = 0; ck < 3; ++ck) {
        short8 ka = *reinterpret_cast<const short8*>(
            &Ks[cur][(mi * 16 + lm) * KSTR + ck * 32 + kg * 8]);
        sc[mi] = __builtin_amdgcn_mfma_f32_16x16x32_bf16(ka, qa[ck], sc[mi], 0, 0, 0);
      }
    }
    __builtin_amdgcn_s_setprio(0);

    // 3+4. pipeline: commit K(c+1), issue V(c+1), issue K(c+2)
    if (c + 1 < nch) {
      commitK(cur ^ 1);
      issueV(c + 1);
    }
    if (c + 2 < nch) issueK(c + 2);

    // 5. scale, tail-mask, LAZY online softmax, pack P
#pragma unroll
    for (int mi = 0; mi < 4; ++mi) sc[mi] *= scale;
    if (nk < KC) {
#pragma unroll
      for (int mi = 0; mi < 4; ++mi)
#pragma unroll
        for (int r = 0; r < 4; ++r)
          if (mi * 16 + kg * 4 + r >= nk) sc[mi][r] = -1e30f;
    }
    f32x4 m4 = sc[0];
#pragma unroll
    for (int mi = 1; mi < 4; ++mi) {
      m4[0] = fmaxf(m4[0], sc[mi][0]); m4[1] = fmaxf(m4[1], sc[mi][1]);
      m4[2] = fmaxf(m4[2], sc[mi][2]); m4[3] = fmaxf(m4[3], sc[mi][3]);
    }
    const float rml = fmaxf(fmaxf(m4[0], m4[1]), fmaxf(m4[2], m4[3]));
    if (!__all(rml - m <= 8.0f)) {   // rare: real max growth -> full reduce
      float rm = rml;
      rm = fmaxf(rm, __shfl_xor(rm, 16));
      rm = fmaxf(rm, __shfl_xor(rm, 32));
      const float mnew = fmaxf(m, rm);
      const float fs = __expf(m - mnew);
      m = mnew;
      l *= fs;
#pragma unroll
      for (int dt = 0; dt < 5; ++dt) oacc[dt] *= fs;
    }
    // common path: NO cross-lane ops. P bounded by e^8.
    f32x4 pp[4];
#pragma unroll
    for (int mi = 0; mi < 4; ++mi) {
#pragma unroll
      for (int r = 0; r < 4; ++r) {
        pp[mi][r] = __expf(sc[mi][r] - m);
        l += pp[mi][r];                 // per-lane partial sum
      }
    }
#pragma unroll
    for (int mi = 0; mi < 4; ++mi) {
      __align__(8) bf16 w[4] = {f2b(pp[mi][0]), f2b(pp[mi][1]),
                                f2b(pp[mi][2]), f2b(pp[mi][3])};
      *reinterpret_cast<uint2*>(&Pl[plbase + mi * 16 + kg * 4]) =
          *reinterpret_cast<const uint2*>(w);
    }

    __syncthreads();  // MIDBAR: Vt(c) visible to all waves before PV

    // 7. O^T += V^T . P^T : 2 key-chunks x 5 d-tiles
    __builtin_amdgcn_s_setprio(1);
#pragma unroll
    for (int kc = 0; kc < 2; ++kc) {
      short8 pb = *reinterpret_cast<const short8*>(&Pl[plbase + kc * 32 + kg * 8]);
#pragma unroll
      for (int dt = 0; dt < 5; ++dt) {
        const int d = dt * 16 + lm;
        short8 va = *reinterpret_cast<const short8*>(
            &Vt[d * VSTR + ((kc * 32 + kg * 8) ^ (((d >> 3) & 7) << 3))]);
        oacc[dt] = __builtin_amdgcn_mfma_f32_16x16x32_bf16(va, pb, oacc[dt], 0, 0, 0);
      }
    }
    __builtin_amdgcn_s_setprio(0);

    __syncthreads();  // ENDBAR: PV(c) reads drained -> next commitV safe
  }

  // ---- epilogue: reduce per-lane l across the 4 kg groups, then store ----
  l += __shfl_xor(l, 16);
  l += __shfl_xor(l, 32);
  if (qrow < s1) {
    const float inv = 1.f / l;
    bf16* op = out + (size_t)qrow * DIM + h * HD;
#pragma unroll
    for (int dt = 0; dt < 5; ++dt) {
      __align__(8) bf16 w[4] = {f2b(oacc[dt][0] * inv), f2b(oacc[dt][1] * inv),
                                f2b(oacc[dt][2] * inv), f2b(oacc[dt][3] * inv)};
      *reinterpret_cast<uint2*>(op + dt * 16 + kg * 4) =
          *reinterpret_cast<const uint2*>(w);
    }
  }
}

// ---------------------------------------------------------------------------
extern "C" void kernel_launch(void* const* d_in, const int* in_sizes, int n_in,
                              void* d_out, int out_size, void* d_ws, size_t ws_size,
                              hipStream_t stream) {
  const float* hs    = (const float*)d_in[0];
  const int*   cu    = (const int*)d_in[1];
  const float* cosb  = (const float*)d_in[2];
  const float* sinb  = (const float*)d_in[3];
  const float* Wqkv  = (const float*)d_in[4];
  const float* bqkv  = (const float*)d_in[5];
  const float* Wproj = (const float*)d_in[6];
  const float* bproj = (const float*)d_in[7];

  // ws: qkv bf16 15.73MB | attn_out bf16 5.24MB | WqkvT 9.83MB | WprojT 3.28MB
  //     | hs_bf16 5.24MB  = 39.3 MB
  bf16* qkv      = (bf16*)d_ws;
  bf16* attn_out = qkv + (size_t)N_TOK * QKV_N;
  bf16* WqkvT    = attn_out + (size_t)N_TOK * DIM;
  bf16* WprojT   = WqkvT + (size_t)QKV_N * DIM;
  bf16* hsb      = WprojT + (size_t)DIM * DIM;

  // 0) fused prep: cast hs + transpose both weights
  prep_kernel<<<dim3(QKV_N / 32, DIM / 32, 3), 256, 0, stream>>>(
      hs, hsb, Wqkv, WqkvT, Wproj, WprojT);

  // 1) qkv = bf16(hsb @ Wqkv + bqkv)
  mfma_gemm<1><<<dim3(QKV_N / 128, N_TOK / 128), 256, 0, stream>>>(
      hsb, WqkvT, bqkv, qkv, N_TOK, QKV_N, DIM);

  // 2) RoPE on q,k
  rope_kernel<<<(N_TOK * 2 * NHEAD * (HD / 2)) / 256, 256, 0, stream>>>(
      qkv, cosb, sinb);

  // 3) MFMA flash attention -> attn_out (bf16); 1D grid + XCD remap
  int nseg = in_sizes[1] - 1;
  int nblk = (N_TOK / 128) * nseg * NHEAD;   // 512 for nseg=2 (divisible by 8)
  attn_mfma_kernel<<<nblk, 512, 0, stream>>>(qkv, cu, attn_out, nseg);

  // 4) out = attn_out @ Wproj + bproj (fp32 out)
  mfma_gemm<0><<<dim3(DIM / 128, N_TOK / 128), 256, 0, stream>>>(
      attn_out, WprojT, bproj, d_out, N_TOK, DIM, DIM);
}

// Round 12
// 114.285 us; speedup vs baseline: 1.2199x; 1.0864x over previous
//
#include <hip/hip_runtime.h>
#include <hip/hip_bf16.h>

// Problem constants (Qwen3.5-VL vision attention)
constexpr int N_TOK  = 2048;
constexpr int DIM    = 1280;
constexpr int NHEAD  = 16;
constexpr int HD     = 80;
constexpr int QKV_N  = 3 * DIM;   // 3840

using bf16 = __hip_bfloat16;
typedef __attribute__((ext_vector_type(4))) float f32x4;
typedef __attribute__((ext_vector_type(8))) short short8;  // 8 bf16 = 4 VGPR

__device__ __forceinline__ float b2f(bf16 x) { return __bfloat162float(x); }
__device__ __forceinline__ bf16  f2b(float x) { return __float2bfloat16(x); }

// async global->LDS, 16B per lane; dest is wave-uniform base + lane*16
typedef const __attribute__((address_space(1))) unsigned int* gas_u32;
typedef __attribute__((address_space(3))) unsigned int* las_u32;
__device__ __forceinline__ void gload_lds16(const void* g, void* l) {
  __builtin_amdgcn_global_load_lds((gas_u32)g, (las_u32)l, 16, 0, 0);
}

// ---------------------------------------------------------------------------
// Fused prep: z=0 cast hs->bf16, z=1 transpose Wqkv, z=2 transpose Wproj.
// ---------------------------------------------------------------------------
__device__ __forceinline__ void transpose_body(const float* __restrict__ W,
                                               bf16* __restrict__ WT, int K, int N) {
  __shared__ float tile[32][33];
  const int n0 = blockIdx.x * 32, k0 = blockIdx.y * 32;
  const int tc = threadIdx.x & 31, tr = threadIdx.x >> 5;
#pragma unroll
  for (int r = tr; r < 32; r += 8)
    tile[r][tc] = W[(size_t)(k0 + r) * N + n0 + tc];
  __syncthreads();
#pragma unroll
  for (int r = tr; r < 32; r += 8)
    WT[(size_t)(n0 + r) * K + k0 + tc] = f2b(tile[tc][r]);
}

__global__ __launch_bounds__(256)
void prep_kernel(const float* __restrict__ hs, bf16* __restrict__ hsb,
                 const float* __restrict__ Wqkv, bf16* __restrict__ WqkvT,
                 const float* __restrict__ Wproj, bf16* __restrict__ WprojT) {
  if (blockIdx.z == 0) {
    const int bid = blockIdx.y * gridDim.x + blockIdx.x;
    if (bid >= (N_TOK * DIM) / 2048) return;
    const int i = bid * 2048 + threadIdx.x * 8;
    const float4 a = *reinterpret_cast<const float4*>(hs + i);
    const float4 b = *reinterpret_cast<const float4*>(hs + i + 4);
    __align__(16) bf16 w[8] = {f2b(a.x), f2b(a.y), f2b(a.z), f2b(a.w),
                               f2b(b.x), f2b(b.y), f2b(b.z), f2b(b.w)};
    *reinterpret_cast<short8*>(hsb + i) = *reinterpret_cast<const short8*>(w);
  } else if (blockIdx.z == 1) {
    transpose_body(Wqkv, WqkvT, DIM, QKV_N);           // grid (120,40)
  } else {
    if (blockIdx.x >= DIM / 32) return;
    transpose_body(Wproj, WprojT, DIM, DIM);           // (40,40)
  }
}

// ---------------------------------------------------------------------------
// m97-style MFMA GEMM (R7-verified): C = A(bf16) @ BT(bf16) + bias(fp32)
// BM=BN=128, BK=64, 4 waves, global_load_lds w16 + pre-swizzled source.
// ---------------------------------------------------------------------------
template <int OBF>  // 1: C bf16, 0: C fp32
__global__ __launch_bounds__(256)
void mfma_gemm(const bf16* __restrict__ A, const bf16* __restrict__ BT,
               const float* __restrict__ bias, void* __restrict__ C,
               int M, int N, int K) {
  __shared__ bf16 As[128 * 64];
  __shared__ bf16 Bs[128 * 64];
  const int tid = threadIdx.x;
  const int wid = tid >> 6, lane = tid & 63;
  const int lm = lane & 15, kg = lane >> 4;
  const int wm = (wid >> 1) * 64, wn = (wid & 1) * 64;
  const int m0 = blockIdx.y * 128, n0 = blockIdx.x * 128;

  const int srow = lane >> 3;
  const int sblk = (lane & 7) ^ srow;

  f32x4 acc[4][4];
#pragma unroll
  for (int i = 0; i < 4; ++i)
#pragma unroll
    for (int j = 0; j < 4; ++j) acc[i][j] = (f32x4){0.f, 0.f, 0.f, 0.f};

  for (int k0 = 0; k0 < K; k0 += 64) {
#pragma unroll
    for (int i = 0; i < 4; ++i) {
      const int slot = i * 4 + wid;
      const int row = slot * 8 + srow;
      gload_lds16(A + (size_t)(m0 + row) * K + k0 + sblk * 8, &As[slot * 512]);
      gload_lds16(BT + (size_t)(n0 + row) * K + k0 + sblk * 8, &Bs[slot * 512]);
    }
    __syncthreads();

#pragma unroll
    for (int kh = 0; kh < 2; ++kh) {
      short8 af[4], bfr[4];
#pragma unroll
      for (int t = 0; t < 4; ++t) {
        const int ar = wm + t * 16 + lm;
        af[t] = *reinterpret_cast<const short8*>(
            &As[ar * 64 + ((kh * 4 + kg) ^ (ar & 7)) * 8]);
        const int br = wn + t * 16 + lm;
        bfr[t] = *reinterpret_cast<const short8*>(
            &Bs[br * 64 + ((kh * 4 + kg) ^ (br & 7)) * 8]);
      }
#pragma unroll
      for (int mi = 0; mi < 4; ++mi)
#pragma unroll
        for (int ni = 0; ni < 4; ++ni)
          acc[mi][ni] = __builtin_amdgcn_mfma_f32_16x16x32_bf16(
              af[mi], bfr[ni], acc[mi][ni], 0, 0, 0);
    }
    __syncthreads();
  }

#pragma unroll
  for (int mi = 0; mi < 4; ++mi) {
#pragma unroll
    for (int ni = 0; ni < 4; ++ni) {
      const int col = n0 + wn + ni * 16 + lm;
      const float bv = bias[col];
#pragma unroll
      for (int r = 0; r < 4; ++r) {
        const int row = m0 + wm + mi * 16 + kg * 4 + r;
        const float v = acc[mi][ni][r] + bv;
        if constexpr (OBF)
          ((bf16*)C)[(size_t)row * N + col] = f2b(v);
        else
          ((float*)C)[(size_t)row * N + col] = v;
      }
    }
  }
}

// ---------------------------------------------------------------------------
// RoPE on q and k (in-place on bf16 qkv workspace). cos/sin fp32.
// ---------------------------------------------------------------------------
__global__ void rope_kernel(bf16* __restrict__ qkv, const float* __restrict__ cosb,
                            const float* __restrict__ sinb) {
  constexpr int HALF = HD / 2;  // 40
  int idx = blockIdx.x * blockDim.x + threadIdx.x;
  int n     = idx / (2 * NHEAD * HALF);
  int rem   = idx % (2 * NHEAD * HALF);
  int which = rem / (NHEAD * HALF);
  int rem2  = rem % (NHEAD * HALF);
  int h     = rem2 / HALF;
  int d     = rem2 % HALF;
  size_t base = (size_t)n * QKV_N + which * DIM + h * HD;
  float x1 = b2f(qkv[base + d]), x2 = b2f(qkv[base + d + HALF]);
  float c1 = cosb[n * HD + d], c2 = cosb[n * HD + d + HALF];
  float s1 = sinb[n * HD + d], s2 = sinb[n * HD + d + HALF];
  qkv[base + d]        = f2b(x1 * c1 - x2 * s1);
  qkv[base + d + HALF] = f2b(x2 * c2 + x1 * s2);
}

// ---------------------------------------------------------------------------
// MFMA flash attention, R12: 4 waves x 32 queries/wave (256 thr, QBLK=128).
// Each K/V LDS fragment read is reused for TWO query-group MFMAs -> wave-
// replicated DS reads halved vs R11 (DS-throughput was the bottleneck).
// Keeps: dbuf K, single Vt + midbar, lazy softmax, XCD remap, defer-max.
// ---------------------------------------------------------------------------
constexpr int KC   = 64;   // keys per chunk
constexpr int KSTR = 104;  // >=96 (in-row d-chunks), 208B rows: 2-way banks
constexpr int VSTR = 88;   // 176B rows: 16B-aligned reads
constexpr int PSTR = 72;   // 144B rows

__global__ __launch_bounds__(256)
void attn_mfma_kernel(const bf16* __restrict__ qkv, const int* __restrict__ cu,
                      bf16* __restrict__ out, int nseg) {
  __shared__ bf16 Ks[2][KC * KSTR];      // 26624 B, cols 80..103 zeroed
  __shared__ bf16 Vt[HD * VSTR];         // 14080 B [d][key^swz]
  __shared__ bf16 Pl[128 * PSTR];        // 18432 B [q][key], per-wave 32 rows

  // XCD-aware remap (bijective: gridDim.x % 8 == 0)
  const int p = blockIdx.x;
  const int lidx = (p & 7) * (gridDim.x >> 3) + (p >> 3);
  const int xt  = lidx & 15;             // q-tile (N_TOK/128 = 16)
  const int seg = (lidx >> 4) % nseg;
  const int h   = (lidx >> 4) / nseg;

  const int s0 = cu[seg], s1 = cu[seg + 1];
  if (s0 + xt * 128 >= s1) return;  // uniform early-exit

  const int tid  = threadIdx.x;
  const int wid  = tid >> 6, lane = tid & 63;
  const int lm = lane & 15, kg = lane >> 4;
  const float scale = 0.11180339887498949f;  // 80^-0.5

  // this lane's two query rows (q-groups qt=0,1 within the wave's 32 queries)
  const int qbase = s0 + xt * 128 + wid * 32 + lm;
  const int qrow0 = qbase, qrow1 = qbase + 16;

  // zero-fill Ks pad columns 80..103 in BOTH buffers (384 slots, 2 rounds)
#pragma unroll
  for (int t = 0; t < 2; ++t) {
    const int s = tid + t * 256;
    if (s < 384) {
      int b = s / 192, rem = s % 192, r = rem / 3, sl = rem % 3;
      *reinterpret_cast<short8*>(&Ks[b][r * KSTR + 80 + sl * 8]) =
          (short8){0, 0, 0, 0, 0, 0, 0, 0};
    }
  }

  // Q B-fragments: qa[ck][qt] = Q[q][d = ck*32 + kg*8 .. +7], zero-padded
  short8 qa[3][2];
#pragma unroll
  for (int ck = 0; ck < 3; ++ck) {
    const int dbase = ck * 32 + kg * 8;
    qa[ck][0] = (qrow0 < s1 && dbase < HD)
        ? *reinterpret_cast<const short8*>(qkv + (size_t)qrow0 * QKV_N + h * HD + dbase)
        : (short8){0, 0, 0, 0, 0, 0, 0, 0};
    qa[ck][1] = (qrow1 < s1 && dbase < HD)
        ? *reinterpret_cast<const short8*>(qkv + (size_t)qrow1 * QKV_N + h * HD + dbase)
        : (short8){0, 0, 0, 0, 0, 0, 0, 0};
  }

  // prefetch regs: K 640 slots over 256 thr (3 rounds), V 160 thr x 4 keys
  short8 kreg[3], vreg[4];
  const int vgrp = tid / 10, vsl = tid % 10;  // valid for tid<160
  auto issueK = [&](int c) {
    const int k0 = s0 + c * KC;
#pragma unroll
    for (int t = 0; t < 3; ++t) {
      const int s = tid + t * 256;
      if (s < 640) {
        const int r = min(k0 + s / 10, s1 - 1);
        kreg[t] = *reinterpret_cast<const short8*>(
            qkv + (size_t)r * QKV_N + DIM + h * HD + (s % 10) * 8);
      }
    }
  };
  auto commitK = [&](int buf) {
#pragma unroll
    for (int t = 0; t < 3; ++t) {
      const int s = tid + t * 256;
      if (s < 640)
        *reinterpret_cast<short8*>(&Ks[buf][(s / 10) * KSTR + (s % 10) * 8]) =
            kreg[t];
    }
  };
  auto issueV = [&](int c) {
    if (tid < 160) {
      const int k0 = s0 + c * KC;
#pragma unroll
      for (int e = 0; e < 4; ++e) {
        const int r = min(k0 + vgrp * 4 + e, s1 - 1);
        vreg[e] = *reinterpret_cast<const short8*>(
            qkv + (size_t)r * QKV_N + 2 * DIM + h * HD + vsl * 8);
      }
    }
  };
  auto commitV = [&]() {
    if (tid < 160) {
      const int r0 = vgrp * 4;
      const int swz = (vsl & 7) << 3;
#pragma unroll
      for (int de = 0; de < 8; ++de) {
        __align__(8) bf16 w[4] = {reinterpret_cast<const bf16*>(&vreg[0])[de],
                                  reinterpret_cast<const bf16*>(&vreg[1])[de],
                                  reinterpret_cast<const bf16*>(&vreg[2])[de],
                                  reinterpret_cast<const bf16*>(&vreg[3])[de]};
        *reinterpret_cast<uint2*>(&Vt[(vsl * 8 + de) * VSTR + (r0 ^ swz)]) =
            *reinterpret_cast<const uint2*>(w);
      }
    }
  };

  f32x4 oacc[5][2];
#pragma unroll
  for (int dt = 0; dt < 5; ++dt) {
    oacc[dt][0] = (f32x4){0.f, 0.f, 0.f, 0.f};
    oacc[dt][1] = (f32x4){0.f, 0.f, 0.f, 0.f};
  }
  float m0v = -1e30f, m1v = -1e30f;   // running max per q-group
  float l0 = 0.f, l1 = 0.f;           // per-lane partial sums
  const int prow0 = (wid * 32 + lm) * PSTR;
  const int prow1 = (wid * 32 + 16 + lm) * PSTR;
  const int nch = (s1 - s0 + KC - 1) / KC;

  issueK(0);
  issueV(0);
  commitK(0);
  if (nch > 1) issueK(1);
  __syncthreads();

  for (int c = 0; c < nch; ++c) {
    const int cur = c & 1;
    const int nk = min(KC, s1 - (s0 + c * KC));

    // 1. commit V(c) into the single Vt buffer (readers drained at endbar)
    commitV();

    // 2. S^T = K . Q^T : 4 key-tiles x 3 d-chunks x 2 q-groups (K reused!)
    f32x4 sc[4][2];
    __builtin_amdgcn_s_setprio(1);
#pragma unroll
    for (int mi = 0; mi < 4; ++mi) {
      sc[mi][0] = (f32x4){0.f, 0.f, 0.f, 0.f};
      sc[mi][1] = (f32x4){0.f, 0.f, 0.f, 0.f};
#pragma unroll
      for (int ck = 0; ck < 3; ++ck) {
        short8 ka = *reinterpret_cast<const short8*>(
            &Ks[cur][(mi * 16 + lm) * KSTR + ck * 32 + kg * 8]);
        sc[mi][0] = __builtin_amdgcn_mfma_f32_16x16x32_bf16(ka, qa[ck][0],
                                                            sc[mi][0], 0, 0, 0);
        sc[mi][1] = __builtin_amdgcn_mfma_f32_16x16x32_bf16(ka, qa[ck][1],
                                                            sc[mi][1], 0, 0, 0);
      }
    }
    __builtin_amdgcn_s_setprio(0);

    // 3+4. pipeline: commit K(c+1), issue V(c+1), issue K(c+2)
    if (c + 1 < nch) {
      commitK(cur ^ 1);
      issueV(c + 1);
    }
    if (c + 2 < nch) issueK(c + 2);

    // 5. scale, tail-mask, LAZY online softmax (both q-groups), pack P
#pragma unroll
    for (int mi = 0; mi < 4; ++mi) {
      sc[mi][0] *= scale;
      sc[mi][1] *= scale;
    }
    if (nk < KC) {
#pragma unroll
      for (int mi = 0; mi < 4; ++mi)
#pragma unroll
        for (int r = 0; r < 4; ++r)
          if (mi * 16 + kg * 4 + r >= nk) {
            sc[mi][0][r] = -1e30f;
            sc[mi][1][r] = -1e30f;
          }
    }
    float rml0 = sc[0][0][0], rml1 = sc[0][1][0];
#pragma unroll
    for (int mi = 0; mi < 4; ++mi)
#pragma unroll
      for (int r = 0; r < 4; ++r) {
        if (mi | r) {
          rml0 = fmaxf(rml0, sc[mi][0][r]);
          rml1 = fmaxf(rml1, sc[mi][1][r]);
        }
      }
    if (!__all(fmaxf(rml0 - m0v, rml1 - m1v) <= 8.0f)) {  // rare full reduce
      float rm0 = rml0, rm1 = rml1;
      rm0 = fmaxf(rm0, __shfl_xor(rm0, 16));
      rm0 = fmaxf(rm0, __shfl_xor(rm0, 32));
      rm1 = fmaxf(rm1, __shfl_xor(rm1, 16));
      rm1 = fmaxf(rm1, __shfl_xor(rm1, 32));
      const float mn0 = fmaxf(m0v, rm0), mn1 = fmaxf(m1v, rm1);
      const float fs0 = __expf(m0v - mn0), fs1 = __expf(m1v - mn1);
      m0v = mn0; m1v = mn1;
      l0 *= fs0; l1 *= fs1;
#pragma unroll
      for (int dt = 0; dt < 5; ++dt) {
        oacc[dt][0] *= fs0;
        oacc[dt][1] *= fs1;
      }
    }
    // common path: NO cross-lane ops. exp in place (P bounded by e^8).
#pragma unroll
    for (int mi = 0; mi < 4; ++mi) {
#pragma unroll
      for (int r = 0; r < 4; ++r) {
        sc[mi][0][r] = __expf(sc[mi][0][r] - m0v);
        l0 += sc[mi][0][r];
        sc[mi][1][r] = __expf(sc[mi][1][r] - m1v);
        l1 += sc[mi][1][r];
      }
    }
#pragma unroll
    for (int mi = 0; mi < 4; ++mi) {
      __align__(8) bf16 w0[4] = {f2b(sc[mi][0][0]), f2b(sc[mi][0][1]),
                                 f2b(sc[mi][0][2]), f2b(sc[mi][0][3])};
      __align__(8) bf16 w1[4] = {f2b(sc[mi][1][0]), f2b(sc[mi][1][1]),
                                 f2b(sc[mi][1][2]), f2b(sc[mi][1][3])};
      *reinterpret_cast<uint2*>(&Pl[prow0 + mi * 16 + kg * 4]) =
          *reinterpret_cast<const uint2*>(w0);
      *reinterpret_cast<uint2*>(&Pl[prow1 + mi * 16 + kg * 4]) =
          *reinterpret_cast<const uint2*>(w1);
    }

    __syncthreads();  // MIDBAR: Vt(c) visible to all waves before PV

    // 7. O^T += V^T . P^T : 2 key-chunks x 5 d-tiles x 2 q-groups (V reused!)
    __builtin_amdgcn_s_setprio(1);
#pragma unroll
    for (int kc = 0; kc < 2; ++kc) {
      short8 pb0 = *reinterpret_cast<const short8*>(&Pl[prow0 + kc * 32 + kg * 8]);
      short8 pb1 = *reinterpret_cast<const short8*>(&Pl[prow1 + kc * 32 + kg * 8]);
#pragma unroll
      for (int dt = 0; dt < 5; ++dt) {
        const int d = dt * 16 + lm;
        short8 va = *reinterpret_cast<const short8*>(
            &Vt[d * VSTR + ((kc * 32 + kg * 8) ^ (((d >> 3) & 7) << 3))]);
        oacc[dt][0] = __builtin_amdgcn_mfma_f32_16x16x32_bf16(va, pb0,
                                                              oacc[dt][0], 0, 0, 0);
        oacc[dt][1] = __builtin_amdgcn_mfma_f32_16x16x32_bf16(va, pb1,
                                                              oacc[dt][1], 0, 0, 0);
      }
    }
    __builtin_amdgcn_s_setprio(0);

    __syncthreads();  // ENDBAR: PV(c) reads drained -> next commitV safe
  }

  // ---- epilogue: reduce per-lane l across kg groups, store both q-groups ----
  l0 += __shfl_xor(l0, 16);
  l0 += __shfl_xor(l0, 32);
  l1 += __shfl_xor(l1, 16);
  l1 += __shfl_xor(l1, 32);
  if (qrow0 < s1) {
    const float inv = 1.f / l0;
    bf16* op = out + (size_t)qrow0 * DIM + h * HD;
#pragma unroll
    for (int dt = 0; dt < 5; ++dt) {
      __align__(8) bf16 w[4] = {f2b(oacc[dt][0][0] * inv), f2b(oacc[dt][0][1] * inv),
                                f2b(oacc[dt][0][2] * inv), f2b(oacc[dt][0][3] * inv)};
      *reinterpret_cast<uint2*>(op + dt * 16 + kg * 4) =
          *reinterpret_cast<const uint2*>(w);
    }
  }
  if (qrow1 < s1) {
    const float inv = 1.f / l1;
    bf16* op = out + (size_t)qrow1 * DIM + h * HD;
#pragma unroll
    for (int dt = 0; dt < 5; ++dt) {
      __align__(8) bf16 w[4] = {f2b(oacc[dt][1][0] * inv), f2b(oacc[dt][1][1] * inv),
                                f2b(oacc[dt][1][2] * inv), f2b(oacc[dt][1][3] * inv)};
      *reinterpret_cast<uint2*>(op + dt * 16 + kg * 4) =
          *reinterpret_cast<const uint2*>(w);
    }
  }
}

// ---------------------------------------------------------------------------
extern "C" void kernel_launch(void* const* d_in, const int* in_sizes, int n_in,
                              void* d_out, int out_size, void* d_ws, size_t ws_size,
                              hipStream_t stream) {
  const float* hs    = (const float*)d_in[0];
  const int*   cu    = (const int*)d_in[1];
  const float* cosb  = (const float*)d_in[2];
  const float* sinb  = (const float*)d_in[3];
  const float* Wqkv  = (const float*)d_in[4];
  const float* bqkv  = (const float*)d_in[5];
  const float* Wproj = (const float*)d_in[6];
  const float* bproj = (const float*)d_in[7];

  // ws: qkv bf16 15.73MB | attn_out bf16 5.24MB | WqkvT 9.83MB | WprojT 3.28MB
  //     | hs_bf16 5.24MB  = 39.3 MB
  bf16* qkv      = (bf16*)d_ws;
  bf16* attn_out = qkv + (size_t)N_TOK * QKV_N;
  bf16* WqkvT    = attn_out + (size_t)N_TOK * DIM;
  bf16* WprojT   = WqkvT + (size_t)QKV_N * DIM;
  bf16* hsb      = WprojT + (size_t)DIM * DIM;

  // 0) fused prep: cast hs + transpose both weights
  prep_kernel<<<dim3(QKV_N / 32, DIM / 32, 3), 256, 0, stream>>>(
      hs, hsb, Wqkv, WqkvT, Wproj, WprojT);

  // 1) qkv = bf16(hsb @ Wqkv + bqkv)
  mfma_gemm<1><<<dim3(QKV_N / 128, N_TOK / 128), 256, 0, stream>>>(
      hsb, WqkvT, bqkv, qkv, N_TOK, QKV_N, DIM);

  // 2) RoPE on q,k
  rope_kernel<<<(N_TOK * 2 * NHEAD * (HD / 2)) / 256, 256, 0, stream>>>(
      qkv, cosb, sinb);

  // 3) MFMA flash attention -> attn_out (bf16); 256 thr, 4 waves x 32 q
  int nseg = in_sizes[1] - 1;
  int nblk = (N_TOK / 128) * nseg * NHEAD;   // 512 for nseg=2 (divisible by 8)
  attn_mfma_kernel<<<nblk, 256, 0, stream>>>(qkv, cu, attn_out, nseg);

  // 4) out = attn_out @ Wproj + bproj (fp32 out)
  mfma_gemm<0><<<dim3(DIM / 128, N_TOK / 128), 256, 0, stream>>>(
      attn_out, WprojT, bproj, d_out, N_TOK, DIM, DIM);
}

// Round 13
// 113.784 us; speedup vs baseline: 1.2253x; 1.0044x over previous
//
#include <hip/hip_runtime.h>
#include <hip/hip_bf16.h>

// Problem constants (Qwen3.5-VL vision attention)
constexpr int N_TOK  = 2048;
constexpr int DIM    = 1280;
constexpr int NHEAD  = 16;
constexpr int HD     = 80;
constexpr int QKV_N  = 3 * DIM;   // 3840

using bf16 = __hip_bfloat16;
typedef __attribute__((ext_vector_type(4)))  float f32x4;
typedef __attribute__((ext_vector_type(16))) float f32x16;
typedef __attribute__((ext_vector_type(8)))  short short8;  // 8 bf16 = 4 VGPR

__device__ __forceinline__ float b2f(bf16 x) { return __bfloat162float(x); }
__device__ __forceinline__ bf16  f2b(float x) { return __float2bfloat16(x); }

// pack two floats -> one u32 of 2 bf16 (lo = first)
__device__ __forceinline__ unsigned int pk2(float a, float b) {
  __align__(4) bf16 t[2] = {f2b(a), f2b(b)};
  return *reinterpret_cast<unsigned int*>(t);
}

// async global->LDS, 16B per lane; dest is wave-uniform base + lane*16
typedef const __attribute__((address_space(1))) unsigned int* gas_u32;
typedef __attribute__((address_space(3))) unsigned int* las_u32;
__device__ __forceinline__ void gload_lds16(const void* g, void* l) {
  __builtin_amdgcn_global_load_lds((gas_u32)g, (las_u32)l, 16, 0, 0);
}

// ---------------------------------------------------------------------------
// Fused prep: z=0 cast hs->bf16, z=1 transpose Wqkv, z=2 transpose Wproj.
// ---------------------------------------------------------------------------
__device__ __forceinline__ void transpose_body(const float* __restrict__ W,
                                               bf16* __restrict__ WT, int K, int N) {
  __shared__ float tile[32][33];
  const int n0 = blockIdx.x * 32, k0 = blockIdx.y * 32;
  const int tc = threadIdx.x & 31, tr = threadIdx.x >> 5;
#pragma unroll
  for (int r = tr; r < 32; r += 8)
    tile[r][tc] = W[(size_t)(k0 + r) * N + n0 + tc];
  __syncthreads();
#pragma unroll
  for (int r = tr; r < 32; r += 8)
    WT[(size_t)(n0 + r) * K + k0 + tc] = f2b(tile[tc][r]);
}

__global__ __launch_bounds__(256)
void prep_kernel(const float* __restrict__ hs, bf16* __restrict__ hsb,
                 const float* __restrict__ Wqkv, bf16* __restrict__ WqkvT,
                 const float* __restrict__ Wproj, bf16* __restrict__ WprojT) {
  if (blockIdx.z == 0) {
    const int bid = blockIdx.y * gridDim.x + blockIdx.x;
    if (bid >= (N_TOK * DIM) / 2048) return;
    const int i = bid * 2048 + threadIdx.x * 8;
    const float4 a = *reinterpret_cast<const float4*>(hs + i);
    const float4 b = *reinterpret_cast<const float4*>(hs + i + 4);
    __align__(16) bf16 w[8] = {f2b(a.x), f2b(a.y), f2b(a.z), f2b(a.w),
                               f2b(b.x), f2b(b.y), f2b(b.z), f2b(b.w)};
    *reinterpret_cast<short8*>(hsb + i) = *reinterpret_cast<const short8*>(w);
  } else if (blockIdx.z == 1) {
    transpose_body(Wqkv, WqkvT, DIM, QKV_N);           // grid (120,40)
  } else {
    if (blockIdx.x >= DIM / 32) return;
    transpose_body(Wproj, WprojT, DIM, DIM);           // (40,40)
  }
}

// ---------------------------------------------------------------------------
// m97-style MFMA GEMM (R7-verified): C = A(bf16) @ BT(bf16) + bias(fp32)
// BM=BN=128, BK=64, 4 waves, global_load_lds w16 + pre-swizzled source.
// ---------------------------------------------------------------------------
template <int OBF>  // 1: C bf16, 0: C fp32
__global__ __launch_bounds__(256)
void mfma_gemm(const bf16* __restrict__ A, const bf16* __restrict__ BT,
               const float* __restrict__ bias, void* __restrict__ C,
               int M, int N, int K) {
  __shared__ bf16 As[128 * 64];
  __shared__ bf16 Bs[128 * 64];
  const int tid = threadIdx.x;
  const int wid = tid >> 6, lane = tid & 63;
  const int lm = lane & 15, kg = lane >> 4;
  const int wm = (wid >> 1) * 64, wn = (wid & 1) * 64;
  const int m0 = blockIdx.y * 128, n0 = blockIdx.x * 128;

  const int srow = lane >> 3;
  const int sblk = (lane & 7) ^ srow;

  f32x4 acc[4][4];
#pragma unroll
  for (int i = 0; i < 4; ++i)
#pragma unroll
    for (int j = 0; j < 4; ++j) acc[i][j] = (f32x4){0.f, 0.f, 0.f, 0.f};

  for (int k0 = 0; k0 < K; k0 += 64) {
#pragma unroll
    for (int i = 0; i < 4; ++i) {
      const int slot = i * 4 + wid;
      const int row = slot * 8 + srow;
      gload_lds16(A + (size_t)(m0 + row) * K + k0 + sblk * 8, &As[slot * 512]);
      gload_lds16(BT + (size_t)(n0 + row) * K + k0 + sblk * 8, &Bs[slot * 512]);
    }
    __syncthreads();

#pragma unroll
    for (int kh = 0; kh < 2; ++kh) {
      short8 af[4], bfr[4];
#pragma unroll
      for (int t = 0; t < 4; ++t) {
        const int ar = wm + t * 16 + lm;
        af[t] = *reinterpret_cast<const short8*>(
            &As[ar * 64 + ((kh * 4 + kg) ^ (ar & 7)) * 8]);
        const int br = wn + t * 16 + lm;
        bfr[t] = *reinterpret_cast<const short8*>(
            &Bs[br * 64 + ((kh * 4 + kg) ^ (br & 7)) * 8]);
      }
#pragma unroll
      for (int mi = 0; mi < 4; ++mi)
#pragma unroll
        for (int ni = 0; ni < 4; ++ni)
          acc[mi][ni] = __builtin_amdgcn_mfma_f32_16x16x32_bf16(
              af[mi], bfr[ni], acc[mi][ni], 0, 0, 0);
    }
    __syncthreads();
  }

#pragma unroll
  for (int mi = 0; mi < 4; ++mi) {
#pragma unroll
    for (int ni = 0; ni < 4; ++ni) {
      const int col = n0 + wn + ni * 16 + lm;
      const float bv = bias[col];
#pragma unroll
      for (int r = 0; r < 4; ++r) {
        const int row = m0 + wm + mi * 16 + kg * 4 + r;
        const float v = acc[mi][ni][r] + bv;
        if constexpr (OBF)
          ((bf16*)C)[(size_t)row * N + col] = f2b(v);
        else
          ((float*)C)[(size_t)row * N + col] = v;
      }
    }
  }
}

// ---------------------------------------------------------------------------
// RoPE on q and k (in-place on bf16 qkv workspace). cos/sin fp32.
// ---------------------------------------------------------------------------
__global__ void rope_kernel(bf16* __restrict__ qkv, const float* __restrict__ cosb,
                            const float* __restrict__ sinb) {
  constexpr int HALF = HD / 2;  // 40
  int idx = blockIdx.x * blockDim.x + threadIdx.x;
  int n     = idx / (2 * NHEAD * HALF);
  int rem   = idx % (2 * NHEAD * HALF);
  int which = rem / (NHEAD * HALF);
  int rem2  = rem % (NHEAD * HALF);
  int h     = rem2 / HALF;
  int d     = rem2 % HALF;
  size_t base = (size_t)n * QKV_N + which * DIM + h * HD;
  float x1 = b2f(qkv[base + d]), x2 = b2f(qkv[base + d + HALF]);
  float c1 = cosb[n * HD + d], c2 = cosb[n * HD + d + HALF];
  float s1 = sinb[n * HD + d], s2 = sinb[n * HD + d + HALF];
  qkv[base + d]        = f2b(x1 * c1 - x2 * s1);
  qkv[base + d + HALF] = f2b(x2 * c2 + x1 * s2);
}

// ---------------------------------------------------------------------------
// MFMA flash attention, R13: 32x32x16 MFMA + in-register P (permlane32_swap).
// Geometry unchanged from R12: 4 waves x 32 q, QBLK=128, dbuf K, single Vt,
// lazy softmax, XCD remap, same staging lambdas, 2 barriers/chunk.
//  QK: S^T = K.Q^T, 2 key-tiles x 5 d-chunks (K=16). D: col=q=lane&31,
//      row=key=(reg&3)+8*(reg>>2)+4*(lane>>5)  [guide m74/m101 verified].
//  P: packed to bf16 words in-register; v_permlane32_swap_b32 exchanges the
//     lane-half packets so each lane assembles its PV B-frag (keys
//     kchunk*16+half*8..+7 for its q). NO P LDS round-trip.
//  PV: O^T += V^T.P^T, 3 d-tiles (d padded 80->96, Vt rows 80-95 zeroed).
// ---------------------------------------------------------------------------
constexpr int KC   = 64;   // keys per chunk
constexpr int KSTR = 104;  // 208B rows; reads at d-offsets 0..72 (+16B) < 80
constexpr int VSTR = 88;   // 176B rows; key XOR swizzle, 16B-aligned reads
constexpr int VROWS = 96;  // 80 real d + 16 zero rows for the dt=2 tile

__global__ __launch_bounds__(256)
void attn_mfma_kernel(const bf16* __restrict__ qkv, const int* __restrict__ cu,
                      bf16* __restrict__ out, int nseg) {
  __shared__ bf16 Ks[2][KC * KSTR];      // 26624 B [key][d]
  __shared__ bf16 Vt[VROWS * VSTR];      // 16896 B [d][key^swz], rows 80+ = 0

  // XCD-aware remap (bijective: gridDim.x % 8 == 0)
  const int p = blockIdx.x;
  const int lidx = (p & 7) * (gridDim.x >> 3) + (p >> 3);
  const int xt  = lidx & 15;             // q-tile (N_TOK/128 = 16)
  const int seg = (lidx >> 4) % nseg;
  const int h   = (lidx >> 4) / nseg;

  const int s0 = cu[seg], s1 = cu[seg + 1];
  if (s0 + xt * 128 >= s1) return;  // uniform early-exit

  const int tid  = threadIdx.x;
  const int wid  = tid >> 6, lane = tid & 63;
  const int l31  = lane & 31;
  const int half = lane >> 5;            // 0/1: which 32-lane half
  const float scale = 0.11180339887498949f;  // 80^-0.5

  const int qrow = s0 + xt * 128 + wid * 32 + l31;

  // zero-fill Vt rows 80..95 once (commitV never touches them)
  if (tid < 176) {
    int r = 80 + tid / 11, sl = tid % 11;
    *reinterpret_cast<short8*>(&Vt[r * VSTR + sl * 8]) =
        (short8){0, 0, 0, 0, 0, 0, 0, 0};
  }

  // Q B-fragments: qa[ck] = Q[q=l31][d = ck*16 + half*8 .. +7]
  short8 qa[5];
#pragma unroll
  for (int ck = 0; ck < 5; ++ck) {
    const int dbase = ck * 16 + half * 8;
    qa[ck] = (qrow < s1)
        ? *reinterpret_cast<const short8*>(qkv + (size_t)qrow * QKV_N + h * HD + dbase)
        : (short8){0, 0, 0, 0, 0, 0, 0, 0};
  }

  // prefetch regs: K 640 slots over 256 thr (3 rounds), V 160 thr x 4 keys
  short8 kreg[3], vreg[4];
  const int vgrp = tid / 10, vsl = tid % 10;  // valid for tid<160
  auto issueK = [&](int c) {
    const int k0 = s0 + c * KC;
#pragma unroll
    for (int t = 0; t < 3; ++t) {
      const int s = tid + t * 256;
      if (s < 640) {
        const int r = min(k0 + s / 10, s1 - 1);
        kreg[t] = *reinterpret_cast<const short8*>(
            qkv + (size_t)r * QKV_N + DIM + h * HD + (s % 10) * 8);
      }
    }
  };
  auto commitK = [&](int buf) {
#pragma unroll
    for (int t = 0; t < 3; ++t) {
      const int s = tid + t * 256;
      if (s < 640)
        *reinterpret_cast<short8*>(&Ks[buf][(s / 10) * KSTR + (s % 10) * 8]) =
            kreg[t];
    }
  };
  auto issueV = [&](int c) {
    if (tid < 160) {
      const int k0 = s0 + c * KC;
#pragma unroll
      for (int e = 0; e < 4; ++e) {
        const int r = min(k0 + vgrp * 4 + e, s1 - 1);
        vreg[e] = *reinterpret_cast<const short8*>(
            qkv + (size_t)r * QKV_N + 2 * DIM + h * HD + vsl * 8);
      }
    }
  };
  auto commitV = [&]() {
    if (tid < 160) {
      const int r0 = vgrp * 4;
      const int swz = (vsl & 7) << 3;
#pragma unroll
      for (int de = 0; de < 8; ++de) {
        __align__(8) bf16 w[4] = {reinterpret_cast<const bf16*>(&vreg[0])[de],
                                  reinterpret_cast<const bf16*>(&vreg[1])[de],
                                  reinterpret_cast<const bf16*>(&vreg[2])[de],
                                  reinterpret_cast<const bf16*>(&vreg[3])[de]};
        *reinterpret_cast<uint2*>(&Vt[(vsl * 8 + de) * VSTR + (r0 ^ swz)]) =
            *reinterpret_cast<const uint2*>(w);
      }
    }
  };

  f32x16 oacc[3];
#pragma unroll
  for (int dt = 0; dt < 3; ++dt)
#pragma unroll
    for (int r = 0; r < 16; ++r) oacc[dt][r] = 0.f;
  float m = -1e30f, l = 0.f;   // per-lane; q's data lives in lanes q, q+32
  const int nch = (s1 - s0 + KC - 1) / KC;

  issueK(0);
  issueV(0);
  commitK(0);
  if (nch > 1) issueK(1);
  __syncthreads();

  for (int c = 0; c < nch; ++c) {
    const int cur = c & 1;
    const int nk = min(KC, s1 - (s0 + c * KC));

    // 1. commit V(c) into the single Vt buffer (readers drained at endbar)
    commitV();

    // 2. S^T = K . Q^T : 2 key-tiles x 5 d-chunks (32x32x16)
    f32x16 sc[2];
    __builtin_amdgcn_s_setprio(1);
#pragma unroll
    for (int kt = 0; kt < 2; ++kt) {
#pragma unroll
      for (int r = 0; r < 16; ++r) sc[kt][r] = 0.f;
#pragma unroll
      for (int ck = 0; ck < 5; ++ck) {
        short8 ka = *reinterpret_cast<const short8*>(
            &Ks[cur][(kt * 32 + l31) * KSTR + ck * 16 + half * 8]);
        sc[kt] = __builtin_amdgcn_mfma_f32_32x32x16_bf16(ka, qa[ck], sc[kt], 0, 0, 0);
      }
    }
    __builtin_amdgcn_s_setprio(0);

    // 3+4. pipeline: commit K(c+1), issue V(c+1), issue K(c+2)
    if (c + 1 < nch) {
      commitK(cur ^ 1);
      issueV(c + 1);
    }
    if (c + 2 < nch) issueK(c + 2);

    // 5. scale, tail-mask, LAZY online softmax
#pragma unroll
    for (int kt = 0; kt < 2; ++kt)
#pragma unroll
      for (int r = 0; r < 16; ++r) sc[kt][r] *= scale;
    if (nk < KC) {
#pragma unroll
      for (int kt = 0; kt < 2; ++kt)
#pragma unroll
        for (int r = 0; r < 16; ++r) {
          const int key = kt * 32 + (r & 3) + 8 * (r >> 2) + 4 * half;
          if (key >= nk) sc[kt][r] = -1e30f;
        }
    }
    float rml = sc[0][0];
#pragma unroll
    for (int kt = 0; kt < 2; ++kt)
#pragma unroll
      for (int r = 0; r < 16; ++r)
        if (kt | r) rml = fmaxf(rml, sc[kt][r]);
    if (!__all(rml - m <= 8.0f)) {   // rare: real max growth -> full reduce
      float rm = fmaxf(rml, __shfl_xor(rml, 32));
      const float mnew = fmaxf(m, rm);
      const float fs = __expf(m - mnew);
      m = mnew;
      l *= fs;
#pragma unroll
      for (int dt = 0; dt < 3; ++dt)
#pragma unroll
        for (int r = 0; r < 16; ++r) oacc[dt][r] *= fs;
    }
    // exp in place; per-lane partial l (P bounded by e^8)
#pragma unroll
    for (int kt = 0; kt < 2; ++kt)
#pragma unroll
      for (int r = 0; r < 16; ++r) {
        sc[kt][r] = __expf(sc[kt][r] - m);
        l += sc[kt][r];
      }

    // 6. P -> bf16 words -> permlane32_swap assembly of PV B-frags.
    //    For (kt, kc2): swap(w[4*kc2+0], w[4*kc2+2]) -> {Bword0, Bword2};
    //                   swap(w[4*kc2+1], w[4*kc2+3]) -> {Bword1, Bword3}.
    unsigned int pbw[4][4];  // [kchunk = kt*2+kc2][word 0..3]
#pragma unroll
    for (int kt = 0; kt < 2; ++kt) {
      unsigned int w[8];
#pragma unroll
      for (int i = 0; i < 8; ++i) w[i] = pk2(sc[kt][2 * i], sc[kt][2 * i + 1]);
#pragma unroll
      for (int kc2 = 0; kc2 < 2; ++kc2) {
        auto r02 = __builtin_amdgcn_permlane32_swap(w[4 * kc2 + 0],
                                                    w[4 * kc2 + 2], false, false);
        auto r13 = __builtin_amdgcn_permlane32_swap(w[4 * kc2 + 1],
                                                    w[4 * kc2 + 3], false, false);
        pbw[kt * 2 + kc2][0] = r02[0];
        pbw[kt * 2 + kc2][1] = r13[0];
        pbw[kt * 2 + kc2][2] = r02[1];
        pbw[kt * 2 + kc2][3] = r13[1];
      }
    }

    __syncthreads();  // MIDBAR: Vt(c) visible to all waves before PV

    // 7. O^T += V^T . P^T : 4 key-chunks x 3 d-tiles (32x32x16)
    __builtin_amdgcn_s_setprio(1);
#pragma unroll
    for (int kc = 0; kc < 4; ++kc) {
      short8 pb = *reinterpret_cast<const short8*>(&pbw[kc][0]);
#pragma unroll
      for (int dt = 0; dt < 3; ++dt) {
        const int d = dt * 32 + l31;
        short8 va = *reinterpret_cast<const short8*>(
            &Vt[d * VSTR + ((kc * 16 + half * 8) ^ (((d >> 3) & 7) << 3))]);
        oacc[dt] = __builtin_amdgcn_mfma_f32_32x32x16_bf16(va, pb, oacc[dt], 0, 0, 0);
      }
    }
    __builtin_amdgcn_s_setprio(0);

    __syncthreads();  // ENDBAR: PV(c) reads drained -> next commitV safe
  }

  // ---- epilogue: l across halves; D row = (reg&3)+8*(reg>>2)+4*half ----
  l += __shfl_xor(l, 32);
  if (qrow < s1) {
    const float inv = 1.f / l;
    bf16* op = out + (size_t)qrow * DIM + h * HD;
#pragma unroll
    for (int dt = 0; dt < 3; ++dt) {
#pragma unroll
      for (int g = 0; g < 4; ++g) {
        const int d = dt * 32 + g * 8 + half * 4;
        if (d < HD) {
          __align__(8) bf16 w[4] = {f2b(oacc[dt][g * 4 + 0] * inv),
                                    f2b(oacc[dt][g * 4 + 1] * inv),
                                    f2b(oacc[dt][g * 4 + 2] * inv),
                                    f2b(oacc[dt][g * 4 + 3] * inv)};
          *reinterpret_cast<uint2*>(op + d) = *reinterpret_cast<const uint2*>(w);
        }
      }
    }
  }
}

// ---------------------------------------------------------------------------
extern "C" void kernel_launch(void* const* d_in, const int* in_sizes, int n_in,
                              void* d_out, int out_size, void* d_ws, size_t ws_size,
                              hipStream_t stream) {
  const float* hs    = (const float*)d_in[0];
  const int*   cu    = (const int*)d_in[1];
  const float* cosb  = (const float*)d_in[2];
  const float* sinb  = (const float*)d_in[3];
  const float* Wqkv  = (const float*)d_in[4];
  const float* bqkv  = (const float*)d_in[5];
  const float* Wproj = (const float*)d_in[6];
  const float* bproj = (const float*)d_in[7];

  // ws: qkv bf16 15.73MB | attn_out bf16 5.24MB | WqkvT 9.83MB | WprojT 3.28MB
  //     | hs_bf16 5.24MB  = 39.3 MB
  bf16* qkv      = (bf16*)d_ws;
  bf16* attn_out = qkv + (size_t)N_TOK * QKV_N;
  bf16* WqkvT    = attn_out + (size_t)N_TOK * DIM;
  bf16* WprojT   = WqkvT + (size_t)QKV_N * DIM;
  bf16* hsb      = WprojT + (size_t)DIM * DIM;

  // 0) fused prep: cast hs + transpose both weights
  prep_kernel<<<dim3(QKV_N / 32, DIM / 32, 3), 256, 0, stream>>>(
      hs, hsb, Wqkv, WqkvT, Wproj, WprojT);

  // 1) qkv = bf16(hsb @ Wqkv + bqkv)
  mfma_gemm<1><<<dim3(QKV_N / 128, N_TOK / 128), 256, 0, stream>>>(
      hsb, WqkvT, bqkv, qkv, N_TOK, QKV_N, DIM);

  // 2) RoPE on q,k
  rope_kernel<<<(N_TOK * 2 * NHEAD * (HD / 2)) / 256, 256, 0, stream>>>(
      qkv, cosb, sinb);

  // 3) MFMA flash attention -> attn_out (bf16); 256 thr, 32x32 MFMA
  int nseg = in_sizes[1] - 1;
  int nblk = (N_TOK / 128) * nseg * NHEAD;   // 512 for nseg=2 (divisible by 8)
  attn_mfma_kernel<<<nblk, 256, 0, stream>>>(qkv, cu, attn_out, nseg);

  // 4) out = attn_out @ Wproj + bproj (fp32 out)
  mfma_gemm<0><<<dim3(DIM / 128, N_TOK / 128), 256, 0, stream>>>(
      attn_out, WprojT, bproj, d_out, N_TOK, DIM, DIM);
}

// Round 14
// 111.385 us; speedup vs baseline: 1.2517x; 1.0215x over previous
//
#include <hip/hip_runtime.h>
#include <hip/hip_bf16.h>

// Problem constants (Qwen3.5-VL vision attention)
constexpr int N_TOK  = 2048;
constexpr int DIM    = 1280;
constexpr int NHEAD  = 16;
constexpr int HD     = 80;
constexpr int QKV_N  = 3 * DIM;   // 3840

using bf16 = __hip_bfloat16;
typedef __attribute__((ext_vector_type(4)))  float f32x4;
typedef __attribute__((ext_vector_type(16))) float f32x16;
typedef __attribute__((ext_vector_type(8)))  short short8;  // 8 bf16 = 4 VGPR

__device__ __forceinline__ float b2f(bf16 x) { return __bfloat162float(x); }
__device__ __forceinline__ bf16  f2b(float x) { return __float2bfloat16(x); }

// pack two floats -> one u32 of 2 bf16 (lo = first)
__device__ __forceinline__ unsigned int pk2(float a, float b) {
  __align__(4) bf16 t[2] = {f2b(a), f2b(b)};
  return *reinterpret_cast<unsigned int*>(t);
}

// async global->LDS, 16B per lane; dest is wave-uniform base + lane*16
typedef const __attribute__((address_space(1))) unsigned int* gas_u32;
typedef __attribute__((address_space(3))) unsigned int* las_u32;
__device__ __forceinline__ void gload_lds16(const void* g, void* l) {
  __builtin_amdgcn_global_load_lds((gas_u32)g, (las_u32)l, 16, 0, 0);
}

// ---------------------------------------------------------------------------
// Fused prep: z=0 cast hs->bf16, z=1 transpose Wqkv, z=2 transpose Wproj.
// ---------------------------------------------------------------------------
__device__ __forceinline__ void transpose_body(const float* __restrict__ W,
                                               bf16* __restrict__ WT, int K, int N) {
  __shared__ float tile[32][33];
  const int n0 = blockIdx.x * 32, k0 = blockIdx.y * 32;
  const int tc = threadIdx.x & 31, tr = threadIdx.x >> 5;
#pragma unroll
  for (int r = tr; r < 32; r += 8)
    tile[r][tc] = W[(size_t)(k0 + r) * N + n0 + tc];
  __syncthreads();
#pragma unroll
  for (int r = tr; r < 32; r += 8)
    WT[(size_t)(n0 + r) * K + k0 + tc] = f2b(tile[tc][r]);
}

__global__ __launch_bounds__(256)
void prep_kernel(const float* __restrict__ hs, bf16* __restrict__ hsb,
                 const float* __restrict__ Wqkv, bf16* __restrict__ WqkvT,
                 const float* __restrict__ Wproj, bf16* __restrict__ WprojT) {
  if (blockIdx.z == 0) {
    const int bid = blockIdx.y * gridDim.x + blockIdx.x;
    if (bid >= (N_TOK * DIM) / 2048) return;
    const int i = bid * 2048 + threadIdx.x * 8;
    const float4 a = *reinterpret_cast<const float4*>(hs + i);
    const float4 b = *reinterpret_cast<const float4*>(hs + i + 4);
    __align__(16) bf16 w[8] = {f2b(a.x), f2b(a.y), f2b(a.z), f2b(a.w),
                               f2b(b.x), f2b(b.y), f2b(b.z), f2b(b.w)};
    *reinterpret_cast<short8*>(hsb + i) = *reinterpret_cast<const short8*>(w);
  } else if (blockIdx.z == 1) {
    transpose_body(Wqkv, WqkvT, DIM, QKV_N);           // grid (120,40)
  } else {
    if (blockIdx.x >= DIM / 32) return;
    transpose_body(Wproj, WprojT, DIM, DIM);           // (40,40)
  }
}

// ---------------------------------------------------------------------------
// m97-style MFMA GEMM (R7-verified): C = A(bf16) @ BT(bf16) + bias(fp32)
// BM=BN=128, BK=64, 4 waves, global_load_lds w16 + pre-swizzled source.
// ---------------------------------------------------------------------------
template <int OBF>  // 1: C bf16, 0: C fp32
__global__ __launch_bounds__(256)
void mfma_gemm(const bf16* __restrict__ A, const bf16* __restrict__ BT,
               const float* __restrict__ bias, void* __restrict__ C,
               int M, int N, int K) {
  __shared__ bf16 As[128 * 64];
  __shared__ bf16 Bs[128 * 64];
  const int tid = threadIdx.x;
  const int wid = tid >> 6, lane = tid & 63;
  const int lm = lane & 15, kg = lane >> 4;
  const int wm = (wid >> 1) * 64, wn = (wid & 1) * 64;
  const int m0 = blockIdx.y * 128, n0 = blockIdx.x * 128;

  const int srow = lane >> 3;
  const int sblk = (lane & 7) ^ srow;

  f32x4 acc[4][4];
#pragma unroll
  for (int i = 0; i < 4; ++i)
#pragma unroll
    for (int j = 0; j < 4; ++j) acc[i][j] = (f32x4){0.f, 0.f, 0.f, 0.f};

  for (int k0 = 0; k0 < K; k0 += 64) {
#pragma unroll
    for (int i = 0; i < 4; ++i) {
      const int slot = i * 4 + wid;
      const int row = slot * 8 + srow;
      gload_lds16(A + (size_t)(m0 + row) * K + k0 + sblk * 8, &As[slot * 512]);
      gload_lds16(BT + (size_t)(n0 + row) * K + k0 + sblk * 8, &Bs[slot * 512]);
    }
    __syncthreads();

#pragma unroll
    for (int kh = 0; kh < 2; ++kh) {
      short8 af[4], bfr[4];
#pragma unroll
      for (int t = 0; t < 4; ++t) {
        const int ar = wm + t * 16 + lm;
        af[t] = *reinterpret_cast<const short8*>(
            &As[ar * 64 + ((kh * 4 + kg) ^ (ar & 7)) * 8]);
        const int br = wn + t * 16 + lm;
        bfr[t] = *reinterpret_cast<const short8*>(
            &Bs[br * 64 + ((kh * 4 + kg) ^ (br & 7)) * 8]);
      }
#pragma unroll
      for (int mi = 0; mi < 4; ++mi)
#pragma unroll
        for (int ni = 0; ni < 4; ++ni)
          acc[mi][ni] = __builtin_amdgcn_mfma_f32_16x16x32_bf16(
              af[mi], bfr[ni], acc[mi][ni], 0, 0, 0);
    }
    __syncthreads();
  }

#pragma unroll
  for (int mi = 0; mi < 4; ++mi) {
#pragma unroll
    for (int ni = 0; ni < 4; ++ni) {
      const int col = n0 + wn + ni * 16 + lm;
      const float bv = bias[col];
#pragma unroll
      for (int r = 0; r < 4; ++r) {
        const int row = m0 + wm + mi * 16 + kg * 4 + r;
        const float v = acc[mi][ni][r] + bv;
        if constexpr (OBF)
          ((bf16*)C)[(size_t)row * N + col] = f2b(v);
        else
          ((float*)C)[(size_t)row * N + col] = v;
      }
    }
  }
}

// ---------------------------------------------------------------------------
// RoPE v2: vectorized, 8 rotate-pairs (16 elems) per thread.
// Thread -> (n, which, h, d-group of 8 in [0,40)). short8 loads/stores.
// ---------------------------------------------------------------------------
__global__ __launch_bounds__(256)
void rope_kernel(bf16* __restrict__ qkv, const float* __restrict__ cosb,
                 const float* __restrict__ sinb) {
  const int idx  = blockIdx.x * 256 + threadIdx.x;   // over N*2*H*5
  const int d0   = (idx % 5) * 8;
  const int h    = (idx / 5) % NHEAD;
  const int whch = (idx / (5 * NHEAD)) % 2;
  const int n    = idx / (10 * NHEAD);
  const size_t base = (size_t)n * QKV_N + whch * DIM + h * HD;

  short8 a = *reinterpret_cast<const short8*>(qkv + base + d0);        // x1
  short8 b = *reinterpret_cast<const short8*>(qkv + base + 40 + d0);   // x2
  const float4 c0 = *reinterpret_cast<const float4*>(cosb + n * HD + d0);
  const float4 c1 = *reinterpret_cast<const float4*>(cosb + n * HD + d0 + 4);
  const float4 c2 = *reinterpret_cast<const float4*>(cosb + n * HD + 40 + d0);
  const float4 c3 = *reinterpret_cast<const float4*>(cosb + n * HD + 44 + d0);
  const float4 s0 = *reinterpret_cast<const float4*>(sinb + n * HD + d0);
  const float4 s1 = *reinterpret_cast<const float4*>(sinb + n * HD + d0 + 4);
  const float4 s2 = *reinterpret_cast<const float4*>(sinb + n * HD + 40 + d0);
  const float4 s3 = *reinterpret_cast<const float4*>(sinb + n * HD + 44 + d0);
  const float* cl = &c0.x;  // c0,c1 contiguous? not guaranteed; use arrays
  float cc1[8] = {c0.x, c0.y, c0.z, c0.w, c1.x, c1.y, c1.z, c1.w};
  float cc2[8] = {c2.x, c2.y, c2.z, c2.w, c3.x, c3.y, c3.z, c3.w};
  float ss1[8] = {s0.x, s0.y, s0.z, s0.w, s1.x, s1.y, s1.z, s1.w};
  float ss2[8] = {s2.x, s2.y, s2.z, s2.w, s3.x, s3.y, s3.z, s3.w};
  (void)cl;

  __align__(16) bf16 o1[8], o2[8];
#pragma unroll
  for (int e = 0; e < 8; ++e) {
    const float x1 = b2f(reinterpret_cast<const bf16*>(&a)[e]);
    const float x2 = b2f(reinterpret_cast<const bf16*>(&b)[e]);
    o1[e] = f2b(x1 * cc1[e] - x2 * ss1[e]);
    o2[e] = f2b(x2 * cc2[e] + x1 * ss2[e]);
  }
  *reinterpret_cast<short8*>(qkv + base + d0)      = *reinterpret_cast<const short8*>(o1);
  *reinterpret_cast<short8*>(qkv + base + 40 + d0) = *reinterpret_cast<const short8*>(o2);
}

// ---------------------------------------------------------------------------
// MFMA flash attention, R14: R13 (32x32 MFMA + in-register P via
// permlane32_swap) + DOUBLE-BUFFERED Vt -> ONE barrier per chunk.
// Per chunk c (cur=c&1): QK(c) from Ks[cur] | commitK/V(c+1)->buf^1 |
// issueK/V(c+2) | softmax+pack+permlane | PV(c) from Vt[cur] | barrier.
// Hazards: writes to buf^1 only touch data whose readers finished before the
// PREVIOUS barrier; reads of buf[cur] were written before the previous
// barrier. Single barrier separates all write->read pairs.
// ---------------------------------------------------------------------------
constexpr int KC   = 64;   // keys per chunk
constexpr int KSTR = 104;  // 208B rows
constexpr int VSTR = 88;   // 176B rows; key XOR swizzle, 16B-aligned reads
constexpr int VROWS = 96;  // 80 real d + 16 zero rows for the dt=2 tile

__global__ __launch_bounds__(256)
void attn_mfma_kernel(const bf16* __restrict__ qkv, const int* __restrict__ cu,
                      bf16* __restrict__ out, int nseg) {
  __shared__ bf16 Ks[2][KC * KSTR];      // 26624 B [key][d]
  __shared__ bf16 Vt[2][VROWS * VSTR];   // 33792 B [d][key^swz], rows 80+ = 0

  // XCD-aware remap (bijective: gridDim.x % 8 == 0)
  const int p = blockIdx.x;
  const int lidx = (p & 7) * (gridDim.x >> 3) + (p >> 3);
  const int xt  = lidx & 15;             // q-tile (N_TOK/128 = 16)
  const int seg = (lidx >> 4) % nseg;
  const int h   = (lidx >> 4) / nseg;

  const int s0 = cu[seg], s1 = cu[seg + 1];
  if (s0 + xt * 128 >= s1) return;  // uniform early-exit

  const int tid  = threadIdx.x;
  const int wid  = tid >> 6, lane = tid & 63;
  const int l31  = lane & 31;
  const int half = lane >> 5;            // 0/1: which 32-lane half
  const float scale = 0.11180339887498949f;  // 80^-0.5

  const int qrow = s0 + xt * 128 + wid * 32 + l31;

  // zero-fill Vt rows 80..95 in BOTH buffers (2 x 176 slots)
#pragma unroll
  for (int t = 0; t < 2; ++t) {
    const int s = tid + t * 256;
    if (s < 352) {
      const int b = s / 176, rem = s % 176;
      const int r = 80 + rem / 11, sl = rem % 11;
      *reinterpret_cast<short8*>(&Vt[b][r * VSTR + sl * 8]) =
          (short8){0, 0, 0, 0, 0, 0, 0, 0};
    }
  }

  // Q B-fragments: qa[ck] = Q[q=l31][d = ck*16 + half*8 .. +7]
  short8 qa[5];
#pragma unroll
  for (int ck = 0; ck < 5; ++ck) {
    const int dbase = ck * 16 + half * 8;
    qa[ck] = (qrow < s1)
        ? *reinterpret_cast<const short8*>(qkv + (size_t)qrow * QKV_N + h * HD + dbase)
        : (short8){0, 0, 0, 0, 0, 0, 0, 0};
  }

  // prefetch regs: K 640 slots over 256 thr (3 rounds), V 160 thr x 4 keys
  short8 kreg[3], vreg[4];
  const int vgrp = tid / 10, vsl = tid % 10;  // valid for tid<160
  auto issueK = [&](int c) {
    const int k0 = s0 + c * KC;
#pragma unroll
    for (int t = 0; t < 3; ++t) {
      const int s = tid + t * 256;
      if (s < 640) {
        const int r = min(k0 + s / 10, s1 - 1);
        kreg[t] = *reinterpret_cast<const short8*>(
            qkv + (size_t)r * QKV_N + DIM + h * HD + (s % 10) * 8);
      }
    }
  };
  auto commitK = [&](int buf) {
#pragma unroll
    for (int t = 0; t < 3; ++t) {
      const int s = tid + t * 256;
      if (s < 640)
        *reinterpret_cast<short8*>(&Ks[buf][(s / 10) * KSTR + (s % 10) * 8]) =
            kreg[t];
    }
  };
  auto issueV = [&](int c) {
    if (tid < 160) {
      const int k0 = s0 + c * KC;
#pragma unroll
      for (int e = 0; e < 4; ++e) {
        const int r = min(k0 + vgrp * 4 + e, s1 - 1);
        vreg[e] = *reinterpret_cast<const short8*>(
            qkv + (size_t)r * QKV_N + 2 * DIM + h * HD + vsl * 8);
      }
    }
  };
  auto commitV = [&](int buf) {
    if (tid < 160) {
      const int r0 = vgrp * 4;
      const int swz = (vsl & 7) << 3;
#pragma unroll
      for (int de = 0; de < 8; ++de) {
        __align__(8) bf16 w[4] = {reinterpret_cast<const bf16*>(&vreg[0])[de],
                                  reinterpret_cast<const bf16*>(&vreg[1])[de],
                                  reinterpret_cast<const bf16*>(&vreg[2])[de],
                                  reinterpret_cast<const bf16*>(&vreg[3])[de]};
        *reinterpret_cast<uint2*>(&Vt[buf][(vsl * 8 + de) * VSTR + (r0 ^ swz)]) =
            *reinterpret_cast<const uint2*>(w);
      }
    }
  };

  f32x16 oacc[3];
#pragma unroll
  for (int dt = 0; dt < 3; ++dt)
#pragma unroll
    for (int r = 0; r < 16; ++r) oacc[dt][r] = 0.f;
  float m = -1e30f, l = 0.f;   // per-lane; q's data lives in lanes q, q+32
  const int nch = (s1 - s0 + KC - 1) / KC;

  issueK(0);
  issueV(0);
  commitK(0);
  commitV(0);
  if (nch > 1) {
    issueK(1);
    issueV(1);
  }
  __syncthreads();

  for (int c = 0; c < nch; ++c) {
    const int cur = c & 1;
    const int nk = min(KC, s1 - (s0 + c * KC));

    // 1. S^T = K . Q^T : 2 key-tiles x 5 d-chunks (32x32x16)
    f32x16 sc[2];
    __builtin_amdgcn_s_setprio(1);
#pragma unroll
    for (int kt = 0; kt < 2; ++kt) {
#pragma unroll
      for (int r = 0; r < 16; ++r) sc[kt][r] = 0.f;
#pragma unroll
      for (int ck = 0; ck < 5; ++ck) {
        short8 ka = *reinterpret_cast<const short8*>(
            &Ks[cur][(kt * 32 + l31) * KSTR + ck * 16 + half * 8]);
        sc[kt] = __builtin_amdgcn_mfma_f32_32x32x16_bf16(ka, qa[ck], sc[kt], 0, 0, 0);
      }
    }
    __builtin_amdgcn_s_setprio(0);

    // 2. pipeline: commit K/V(c+1) into buf^1, issue K/V(c+2)
    if (c + 1 < nch) {
      commitK(cur ^ 1);
      commitV(cur ^ 1);
    }
    if (c + 2 < nch) {
      issueK(c + 2);
      issueV(c + 2);
    }

    // 3. scale, tail-mask, LAZY online softmax
#pragma unroll
    for (int kt = 0; kt < 2; ++kt)
#pragma unroll
      for (int r = 0; r < 16; ++r) sc[kt][r] *= scale;
    if (nk < KC) {
#pragma unroll
      for (int kt = 0; kt < 2; ++kt)
#pragma unroll
        for (int r = 0; r < 16; ++r) {
          const int key = kt * 32 + (r & 3) + 8 * (r >> 2) + 4 * half;
          if (key >= nk) sc[kt][r] = -1e30f;
        }
    }
    float rml = sc[0][0];
#pragma unroll
    for (int kt = 0; kt < 2; ++kt)
#pragma unroll
      for (int r = 0; r < 16; ++r)
        if (kt | r) rml = fmaxf(rml, sc[kt][r]);
    if (!__all(rml - m <= 8.0f)) {   // rare: real max growth -> full reduce
      float rm = fmaxf(rml, __shfl_xor(rml, 32));
      const float mnew = fmaxf(m, rm);
      const float fs = __expf(m - mnew);
      m = mnew;
      l *= fs;
#pragma unroll
      for (int dt = 0; dt < 3; ++dt)
#pragma unroll
        for (int r = 0; r < 16; ++r) oacc[dt][r] *= fs;
    }
    // exp in place; per-lane partial l (P bounded by e^8)
#pragma unroll
    for (int kt = 0; kt < 2; ++kt)
#pragma unroll
      for (int r = 0; r < 16; ++r) {
        sc[kt][r] = __expf(sc[kt][r] - m);
        l += sc[kt][r];
      }

    // 4. P -> bf16 words -> permlane32_swap assembly of PV B-frags.
    unsigned int pbw[4][4];  // [kchunk = kt*2+kc2][word 0..3]
#pragma unroll
    for (int kt = 0; kt < 2; ++kt) {
      unsigned int w[8];
#pragma unroll
      for (int i = 0; i < 8; ++i) w[i] = pk2(sc[kt][2 * i], sc[kt][2 * i + 1]);
#pragma unroll
      for (int kc2 = 0; kc2 < 2; ++kc2) {
        auto r02 = __builtin_amdgcn_permlane32_swap(w[4 * kc2 + 0],
                                                    w[4 * kc2 + 2], false, false);
        auto r13 = __builtin_amdgcn_permlane32_swap(w[4 * kc2 + 1],
                                                    w[4 * kc2 + 3], false, false);
        pbw[kt * 2 + kc2][0] = r02[0];
        pbw[kt * 2 + kc2][1] = r13[0];
        pbw[kt * 2 + kc2][2] = r02[1];
        pbw[kt * 2 + kc2][3] = r13[1];
      }
    }

    // 5. O^T += V^T . P^T : 4 key-chunks x 3 d-tiles (32x32x16)
    __builtin_amdgcn_s_setprio(1);
#pragma unroll
    for (int kc = 0; kc < 4; ++kc) {
      short8 pb = *reinterpret_cast<const short8*>(&pbw[kc][0]);
#pragma unroll
      for (int dt = 0; dt < 3; ++dt) {
        const int d = dt * 32 + l31;
        short8 va = *reinterpret_cast<const short8*>(
            &Vt[cur][d * VSTR + ((kc * 16 + half * 8) ^ (((d >> 3) & 7) << 3))]);
        oacc[dt] = __builtin_amdgcn_mfma_f32_32x32x16_bf16(va, pb, oacc[dt], 0, 0, 0);
      }
    }
    __builtin_amdgcn_s_setprio(0);

    __syncthreads();  // single barrier: seals buf^1 writes, frees buf[cur]
  }

  // ---- epilogue: l across halves; D row = (reg&3)+8*(reg>>2)+4*half ----
  l += __shfl_xor(l, 32);
  if (qrow < s1) {
    const float inv = 1.f / l;
    bf16* op = out + (size_t)qrow * DIM + h * HD;
#pragma unroll
    for (int dt = 0; dt < 3; ++dt) {
#pragma unroll
      for (int g = 0; g < 4; ++g) {
        const int d = dt * 32 + g * 8 + half * 4;
        if (d < HD) {
          __align__(8) bf16 w[4] = {f2b(oacc[dt][g * 4 + 0] * inv),
                                    f2b(oacc[dt][g * 4 + 1] * inv),
                                    f2b(oacc[dt][g * 4 + 2] * inv),
                                    f2b(oacc[dt][g * 4 + 3] * inv)};
          *reinterpret_cast<uint2*>(op + d) = *reinterpret_cast<const uint2*>(w);
        }
      }
    }
  }
}

// ---------------------------------------------------------------------------
extern "C" void kernel_launch(void* const* d_in, const int* in_sizes, int n_in,
                              void* d_out, int out_size, void* d_ws, size_t ws_size,
                              hipStream_t stream) {
  const float* hs    = (const float*)d_in[0];
  const int*   cu    = (const int*)d_in[1];
  const float* cosb  = (const float*)d_in[2];
  const float* sinb  = (const float*)d_in[3];
  const float* Wqkv  = (const float*)d_in[4];
  const float* bqkv  = (const float*)d_in[5];
  const float* Wproj = (const float*)d_in[6];
  const float* bproj = (const float*)d_in[7];

  // ws: qkv bf16 15.73MB | attn_out bf16 5.24MB | WqkvT 9.83MB | WprojT 3.28MB
  //     | hs_bf16 5.24MB  = 39.3 MB
  bf16* qkv      = (bf16*)d_ws;
  bf16* attn_out = qkv + (size_t)N_TOK * QKV_N;
  bf16* WqkvT    = attn_out + (size_t)N_TOK * DIM;
  bf16* WprojT   = WqkvT + (size_t)QKV_N * DIM;
  bf16* hsb      = WprojT + (size_t)DIM * DIM;

  // 0) fused prep: cast hs + transpose both weights
  prep_kernel<<<dim3(QKV_N / 32, DIM / 32, 3), 256, 0, stream>>>(
      hs, hsb, Wqkv, WqkvT, Wproj, WprojT);

  // 1) qkv = bf16(hsb @ Wqkv + bqkv)
  mfma_gemm<1><<<dim3(QKV_N / 128, N_TOK / 128), 256, 0, stream>>>(
      hsb, WqkvT, bqkv, qkv, N_TOK, QKV_N, DIM);

  // 2) RoPE on q,k (vectorized: 8 pairs/thread)
  rope_kernel<<<(N_TOK * 2 * NHEAD * 5) / 256, 256, 0, stream>>>(
      qkv, cosb, sinb);

  // 3) MFMA flash attention -> attn_out (bf16); 256 thr, 32x32 MFMA, V dbuf
  int nseg = in_sizes[1] - 1;
  int nblk = (N_TOK / 128) * nseg * NHEAD;   // 512 for nseg=2 (divisible by 8)
  attn_mfma_kernel<<<nblk, 256, 0, stream>>>(qkv, cu, attn_out, nseg);

  // 4) out = attn_out @ Wproj + bproj (fp32 out)
  mfma_gemm<0><<<dim3(DIM / 128, N_TOK / 128), 256, 0, stream>>>(
      attn_out, WprojT, bproj, d_out, N_TOK, DIM, DIM);
}